// Round 9
// baseline (319.833 us; speedup 1.0000x reference)
//
#include <hip/hip_runtime.h>
#include <hip/hip_bf16.h>

#define IN_F 108   // concat(x[107], votes[1])
#define XD   107
#define HID  128
#define OUTD 64
#define CHUNK 1024 // scan chunk per block
#define SEG_NODES 512
#define W1N (IN_F * HID)   // 13824
#define W2N (HID * HID)    // 16384 (W2l|W2r merged)

typedef unsigned short ushort_t;
typedef unsigned int uint_t;

__device__ inline void atomicMaxF(float* addr, float val) {
    if (val >= 0.f) atomicMax((int*)addr, __float_as_int(val));
    else            atomicMin((unsigned int*)addr, __float_as_uint(val));
}

__device__ inline ushort_t f2bf(float f) {
    uint_t b = __float_as_uint(f);
    return (ushort_t)((b + 0x7fffu + ((b >> 16) & 1u)) >> 16);   // RNE
}

__device__ inline float bf2f(ushort_t u) {
    return __uint_as_float((uint_t)u << 16);
}

__device__ inline uint_t pack2(float lo, float hi) {
    return (uint_t)f2bf(lo) | ((uint_t)f2bf(hi) << 16);
}

// unpack uint2 (4 bf16) -> float4
__device__ inline float4 upk(uint2 w) {
    return make_float4(__uint_as_float(w.x << 16),
                       __uint_as_float(w.x & 0xffff0000u),
                       __uint_as_float(w.y << 16),
                       __uint_as_float(w.y & 0xffff0000u));
}

__device__ inline float4 fma4(float a, const float4 b, float4 c) {
    c.x += a * b.x; c.y += a * b.y; c.z += a * b.z; c.w += a * b.w; return c;
}

__global__ void init_out_kernel(float* out, int n) {
    int i = blockIdx.x * 256 + threadIdx.x;
    if (i < n) out[i] = -__builtin_inff();
}

// ---- CSR build ----------------------------------------------------------
__global__ void hist_kernel(const int* __restrict__ dst, int* __restrict__ deg_i, int E) {
    int e = blockIdx.x * 256 + threadIdx.x;
    if (e < E) atomicAdd(&deg_i[dst[e]], 1);
}

__global__ __launch_bounds__(256) void chunk_sum_kernel(const int* __restrict__ deg_i,
                                                        int* __restrict__ bsum, int N) {
    int base = blockIdx.x * CHUNK;
    int v = 0;
    for (int i = threadIdx.x; i < CHUNK; i += 256) {
        int idx = base + i;
        if (idx < N) v += deg_i[idx];
    }
#pragma unroll
    for (int d = 1; d < 64; d <<= 1) v += __shfl_xor(v, d);
    __shared__ int red[4];
    int wid = threadIdx.x >> 6;
    if ((threadIdx.x & 63) == 0) red[wid] = v;
    __syncthreads();
    if (threadIdx.x == 0) bsum[blockIdx.x] = red[0] + red[1] + red[2] + red[3];
}

__global__ __launch_bounds__(64) void scan_bsum_kernel(const int* __restrict__ bsum,
                                                       int* __restrict__ bsum_ex, int nb) {
    int lane = threadIdx.x;
    int carry = 0;
    for (int b = 0; b < nb; b += 64) {
        int i = b + lane;
        int orig = (i < nb) ? bsum[i] : 0;
        int v = orig;
#pragma unroll
        for (int d = 1; d < 64; d <<= 1) {
            int t = __shfl_up(v, d);
            if (lane >= d) v += t;
        }
        if (i < nb) bsum_ex[i] = carry + v - orig;
        carry += __shfl(v, 63);
    }
}

__global__ __launch_bounds__(256) void write_rows_kernel(const int* __restrict__ deg_i,
                                                         const int* __restrict__ bsum_ex,
                                                         int* __restrict__ row_start,
                                                         int* __restrict__ cursor,
                                                         int N, int E) {
    __shared__ int s[256];
    int base = blockIdx.x * CHUNK;
    int i0 = base + threadIdx.x * 4;
    int d0 = 0, d1 = 0, d2 = 0, d3 = 0;
    if (i0 + 3 < N) {
        int4 q = *(const int4*)(deg_i + i0);
        d0 = q.x; d1 = q.y; d2 = q.z; d3 = q.w;
    } else {
        if (i0 + 0 < N) d0 = deg_i[i0 + 0];
        if (i0 + 1 < N) d1 = deg_i[i0 + 1];
        if (i0 + 2 < N) d2 = deg_i[i0 + 2];
        if (i0 + 3 < N) d3 = deg_i[i0 + 3];
    }
    int tsum = d0 + d1 + d2 + d3;
    s[threadIdx.x] = tsum;
    __syncthreads();
    for (int d = 1; d < 256; d <<= 1) {
        int t = (threadIdx.x >= d) ? s[threadIdx.x - d] : 0;
        __syncthreads();
        s[threadIdx.x] += t;
        __syncthreads();
    }
    int off = bsum_ex[blockIdx.x] + s[threadIdx.x] - tsum;
    if (i0 + 0 < N) { row_start[i0 + 0] = off; cursor[i0 + 0] = off; off += d0; }
    if (i0 + 1 < N) { row_start[i0 + 1] = off; cursor[i0 + 1] = off; off += d1; }
    if (i0 + 2 < N) { row_start[i0 + 2] = off; cursor[i0 + 2] = off; off += d2; }
    if (i0 + 3 < N) { row_start[i0 + 3] = off; cursor[i0 + 3] = off; off += d3; }
    if (blockIdx.x == 0 && threadIdx.x == 0) row_start[N] = E;
}

__global__ void place_kernel(const int* __restrict__ src, const int* __restrict__ dst,
                             int* __restrict__ cursor, int* __restrict__ sorted_src, int E) {
    int e = blockIdx.x * 256 + threadIdx.x;
    if (e >= E) return;
    int pos = atomicAdd(&cursor[dst[e]], 1);
    sorted_src[pos] = src[e];
}

// ---- bf16 copy of h0 ----------------------------------------------------
__global__ void convert_kernel(const float* __restrict__ x, const float* __restrict__ votes,
                               ushort_t* __restrict__ xb, int N) {
    int idx = blockIdx.x * 256 + threadIdx.x;
    if (idx >= N * IN_F) return;
    int n = idx / IN_F, f = idx - n * IN_F;
    float v = (f < XD) ? x[n * XD + f] : votes[n];
    xb[idx] = f2bf(v);
}

// ---- weights -> bf16 (once per launch; w2b = [W2l | W2r] merged) --------
__global__ void convertw_kernel(const float* __restrict__ W1l, const float* __restrict__ W1r,
                                const float* __restrict__ W2l, const float* __restrict__ W2r,
                                ushort_t* __restrict__ w1lb, ushort_t* __restrict__ w1rb,
                                ushort_t* __restrict__ w2b) {
    int i = blockIdx.x * 256 + threadIdx.x;
    if (i < W1N) {
        w1lb[i] = f2bf(W1l[i]);
        w1rb[i] = f2bf(W1r[i]);
    }
    int j = i - W1N;
    if (j >= 0 && j < W2N) {
        int k = j >> 7, c = j & 127;
        float v = (c < OUTD) ? W2l[k * OUTD + c] : W2r[k * OUTD + (c - OUTD)];
        w2b[j] = f2bf(v);
    }
}

// ---- gather-mean layer 1 (bf16 in, f32 accum, bf16 out, pre-divided) ----
__global__ __launch_bounds__(256) void gather1_kernel(
        const ushort_t* __restrict__ xb,
        const int* __restrict__ row_start, const int* __restrict__ sorted_src,
        ushort_t* __restrict__ agg1b, int N) {
    int node = (blockIdx.x * 256 + threadIdx.x) >> 6;
    int lane = threadIdx.x & 63;
    if (node >= N) return;
    int rs = row_start[node], re = row_start[node + 1];
    int h  = lane >> 5;
    int l2 = lane & 31;
    float a0 = 0.f, a1 = 0.f, a2 = 0.f, a3 = 0.f;
    for (int k0 = rs; k0 < re; k0 += 64) {
        int cnt = min(64, re - k0);
        int sl = sorted_src[k0 + min(lane, cnt - 1)];
        for (int t = 0; t < cnt; t += 2) {
            int tt = min(t + h, cnt - 1);
            int s = __shfl(sl, tt);
            if (t + h < cnt && l2 < 27) {
                uint2 w = *(const uint2*)(xb + s * IN_F + 4 * l2);
                a0 += __uint_as_float(w.x << 16);
                a1 += __uint_as_float(w.x & 0xffff0000u);
                a2 += __uint_as_float(w.y << 16);
                a3 += __uint_as_float(w.y & 0xffff0000u);
            }
        }
    }
    a0 += __shfl_xor(a0, 32);
    a1 += __shfl_xor(a1, 32);
    a2 += __shfl_xor(a2, 32);
    a3 += __shfl_xor(a3, 32);
    float inv = 1.f / fmaxf((float)(re - rs), 1.f);
    if (lane < 27) {
        ushort4 p;
        p.x = f2bf(a0 * inv);
        p.y = f2bf(a1 * inv);
        p.z = f2bf(a2 * inv);
        p.w = f2bf(a3 * inv);
        *(ushort4*)(agg1b + node * IN_F + 4 * lane) = p;
    }
}

// ---- gather-mean of u (bf16, 64 dims) -----------------------------------
__global__ __launch_bounds__(256) void gatheru_kernel(
        const ushort_t* __restrict__ ub,
        const int* __restrict__ row_start, const int* __restrict__ sorted_src,
        float* __restrict__ aggu, int N) {
    int node = (blockIdx.x * 256 + threadIdx.x) >> 6;
    int lane = threadIdx.x & 63;
    if (node >= N) return;
    int rs = row_start[node], re = row_start[node + 1];
    int g  = lane >> 4;
    int l4 = lane & 15;
    float a0 = 0.f, a1 = 0.f, a2 = 0.f, a3 = 0.f;
    for (int k0 = rs; k0 < re; k0 += 64) {
        int cnt = min(64, re - k0);
        int sl = sorted_src[k0 + min(lane, cnt - 1)];
        for (int t = 0; t < cnt; t += 4) {
            int tt = min(t + g, cnt - 1);
            int s = __shfl(sl, tt);
            if (t + g < cnt) {
                uint2 w = *(const uint2*)(ub + (s << 6) + 4 * l4);
                a0 += __uint_as_float(w.x << 16);
                a1 += __uint_as_float(w.x & 0xffff0000u);
                a2 += __uint_as_float(w.y << 16);
                a3 += __uint_as_float(w.y & 0xffff0000u);
            }
        }
    }
    a0 += __shfl_xor(a0, 16); a0 += __shfl_xor(a0, 32);
    a1 += __shfl_xor(a1, 16); a1 += __shfl_xor(a1, 32);
    a2 += __shfl_xor(a2, 16); a2 += __shfl_xor(a2, 32);
    a3 += __shfl_xor(a3, 16); a3 += __shfl_xor(a3, 32);
    float inv = 1.f / fmaxf((float)(re - rs), 1.f);
    if (lane < 16) {
        *(float4*)(aggu + (node << 6) + 4 * lane) =
            make_float4(a0 * inv, a1 * inv, a2 * inv, a3 * inv);
    }
}

// ---- fused dense: h1 = relu([agg|h0]@W1 + b1); u|v = h1 @ [W2l|W2r] -----
// All operands bf16 (A-tile in LDS bf16, weights bf16 from global).
// LDS 14.3 KB -> 8 blocks/CU. h1 never written to global.
#define T1_M 32
#define A_STRIDE_U 112   // uints per row: 54 ag + 2 pad? no: [0,54)=ag, [56,110)=h0, stride 112
#define H1_STRIDE_S 136  // ushorts per h1 row
__global__ __launch_bounds__(256) void gemm1_kernel(
        const ushort_t* __restrict__ xb, const ushort_t* __restrict__ agg1b,
        const ushort_t* __restrict__ w1lb, const ushort_t* __restrict__ w1rb,
        const ushort_t* __restrict__ w2b, const float* __restrict__ b1,
        ushort_t* __restrict__ ub, float* __restrict__ vv, int N) {
    __shared__ uint_t smem_u[T1_M * A_STRIDE_U];     // 14336 B
    int n0 = blockIdx.x * T1_M;
    // stage A: ag rows (54 uints) at col 0, h0 rows at uint col 56
    for (int i = threadIdx.x; i < T1_M * 54; i += 256) {
        int m = i / 54, c = i - m * 54;
        int n = n0 + m;
        uint_t ag = 0u, h0 = 0u;
        if (n < N) {
            ag = ((const uint_t*)(agg1b + n * IN_F))[c];
            h0 = ((const uint_t*)(xb + n * IN_F))[c];
        }
        smem_u[m * A_STRIDE_U + c] = ag;
        smem_u[m * A_STRIDE_U + 56 + c] = h0;
    }
    __syncthreads();

    const ushort_t* sA = (const ushort_t*)smem_u;    // row stride 224 ushorts
    int jq = threadIdx.x & 31;          // j0 = jq*4
    int mq = threadIdx.x >> 5;          // rows mq*4+mm
    float4 acc[4] = {};
    const ushort_t* wl = w1lb + jq * 4;
    const ushort_t* wr = w1rb + jq * 4;
#pragma unroll 2
    for (int k = 0; k < IN_F; k += 4) {
        float4 wlv[4], wrv[4];
#pragma unroll
        for (int kk = 0; kk < 4; ++kk) {
            wlv[kk] = upk(*(const uint2*)(wl + (k + kk) * HID));
            wrv[kk] = upk(*(const uint2*)(wr + (k + kk) * HID));
        }
#pragma unroll
        for (int mm = 0; mm < 4; ++mm) {
            const int rb = (mq * 4 + mm) * 224;
            float4 ag = upk(*(const uint2*)(sA + rb + k));
            float4 h0 = upk(*(const uint2*)(sA + rb + 112 + k));
            acc[mm] = fma4(ag.x, wlv[0], acc[mm]);
            acc[mm] = fma4(ag.y, wlv[1], acc[mm]);
            acc[mm] = fma4(ag.z, wlv[2], acc[mm]);
            acc[mm] = fma4(ag.w, wlv[3], acc[mm]);
            acc[mm] = fma4(h0.x, wrv[0], acc[mm]);
            acc[mm] = fma4(h0.y, wrv[1], acc[mm]);
            acc[mm] = fma4(h0.z, wrv[2], acc[mm]);
            acc[mm] = fma4(h0.w, wrv[3], acc[mm]);
        }
    }
    float4 bv = *(const float4*)(b1 + jq * 4);
    float4 rr[4];
#pragma unroll
    for (int mm = 0; mm < 4; ++mm) {
        rr[mm].x = fmaxf(acc[mm].x + bv.x, 0.f);
        rr[mm].y = fmaxf(acc[mm].y + bv.y, 0.f);
        rr[mm].z = fmaxf(acc[mm].z + bv.z, 0.f);
        rr[mm].w = fmaxf(acc[mm].w + bv.w, 0.f);
    }

    // phase 2: h1 (bf16) into LDS, then [u|v] = h1 @ w2b
    __syncthreads();
    ushort_t* sh1 = (ushort_t*)smem_u;               // row stride H1_STRIDE_S
#pragma unroll
    for (int mm = 0; mm < 4; ++mm) {
        uint2 p;
        p.x = pack2(rr[mm].x, rr[mm].y);
        p.y = pack2(rr[mm].z, rr[mm].w);
        *(uint2*)(sh1 + (mq * 4 + mm) * H1_STRIDE_S + jq * 4) = p;
    }
    __syncthreads();

    int jq2 = threadIdx.x & 31;         // combined j = jq2*4 over [u(0..63)|v(64..127)]
    int mq2 = threadIdx.x >> 5;
    float4 acc2[4] = {};
    const ushort_t* w2 = w2b + jq2 * 4;
#pragma unroll 2
    for (int k = 0; k < HID; k += 4) {
        float4 wv[4];
#pragma unroll
        for (int kk = 0; kk < 4; ++kk)
            wv[kk] = upk(*(const uint2*)(w2 + (k + kk) * HID));
#pragma unroll
        for (int mm = 0; mm < 4; ++mm) {
            float4 hv = upk(*(const uint2*)(sh1 + (mq2 * 4 + mm) * H1_STRIDE_S + k));
            acc2[mm] = fma4(hv.x, wv[0], acc2[mm]);
            acc2[mm] = fma4(hv.y, wv[1], acc2[mm]);
            acc2[mm] = fma4(hv.z, wv[2], acc2[mm]);
            acc2[mm] = fma4(hv.w, wv[3], acc2[mm]);
        }
    }

#pragma unroll
    for (int mm = 0; mm < 4; ++mm) {
        int n = n0 + mq2 * 4 + mm;
        if (n < N) {
            if (jq2 < 16) {
                ushort4 p;
                p.x = f2bf(acc2[mm].x);
                p.y = f2bf(acc2[mm].y);
                p.z = f2bf(acc2[mm].z);
                p.w = f2bf(acc2[mm].w);
                *(ushort4*)(ub + (n << 6) + jq2 * 4) = p;
            } else {
                *(float4*)(vv + (n << 6) + (jq2 - 16) * 4) = acc2[mm];
            }
        }
    }
}

// ---- finalize: h2 = aggu + v + b2, then run-length segment-max ----------
__global__ __launch_bounds__(256) void finalize_kernel(
        const float* __restrict__ aggu, const float* __restrict__ vv,
        const float* __restrict__ b2, const int* __restrict__ batch,
        float* __restrict__ out, int N) {
    int j  = threadIdx.x & 63;
    int nq = threadIdx.x >> 6;
    int n0 = blockIdx.x * SEG_NODES;
    float bj = b2[j];
    int curg = -1;
    float curm = -__builtin_inff();
    for (int m = nq; m < SEG_NODES; m += 4) {
        int n = n0 + m;
        if (n >= N) break;
        int g = batch[n];
        float v = aggu[(n << 6) + j] + vv[(n << 6) + j] + bj;
        if (g != curg) {
            if (curg >= 0) atomicMaxF(&out[(curg << 6) + j], curm);
            curg = g;
            curm = v;
        } else {
            curm = fmaxf(curm, v);
        }
    }
    if (curg >= 0) atomicMaxF(&out[(curg << 6) + j], curm);
}

static inline size_t align256(size_t v) { return (v + 255) & ~(size_t)255; }

extern "C" void kernel_launch(void* const* d_in, const int* in_sizes, int n_in,
                              void* d_out, int out_size, void* d_ws, size_t ws_size,
                              hipStream_t stream) {
    const float* x     = (const float*)d_in[0];
    const float* votes = (const float*)d_in[1];
    const int*   eidx  = (const int*)d_in[2];
    const int*   batch = (const int*)d_in[3];
    const float* W1l   = (const float*)d_in[4];
    const float* b1    = (const float*)d_in[5];
    const float* W1r   = (const float*)d_in[6];
    const float* W2l   = (const float*)d_in[7];
    const float* b2    = (const float*)d_in[8];
    const float* W2r   = (const float*)d_in[9];
    float* out = (float*)d_out;

    const int N = in_sizes[1];
    const int E = in_sizes[2] / 2;
    const int* src = eidx;
    const int* dst = eidx + E;
    const int nb = (N + CHUNK - 1) / CHUNK;

    char* ws = (char*)d_ws;
    size_t off = 0;
    int* deg_i      = (int*)(ws + off); off = align256(off + (size_t)N * 4);
    int* row_start  = (int*)(ws + off); off = align256(off + (size_t)(N + 1) * 4);
    int* cursor     = (int*)(ws + off); off = align256(off + (size_t)N * 4);
    int* bsum       = (int*)(ws + off); off = align256(off + (size_t)nb * 4);
    int* bsum_ex    = (int*)(ws + off); off = align256(off + (size_t)nb * 4);
    int* sorted_src = (int*)(ws + off); off = align256(off + (size_t)E * 4);
    ushort_t* xb    = (ushort_t*)(ws + off); off = align256(off + (size_t)N * IN_F * 2);
    ushort_t* agg1b = (ushort_t*)(ws + off); off = align256(off + (size_t)N * IN_F * 2);
    ushort_t* ub    = (ushort_t*)(ws + off); off = align256(off + (size_t)N * OUTD * 2);
    float* vv       = (float*)(ws + off); off = align256(off + (size_t)N * OUTD * 4);
    float* aggu     = (float*)(ws + off); off = align256(off + (size_t)N * OUTD * 4);
    ushort_t* w1lb  = (ushort_t*)(ws + off); off = align256(off + (size_t)W1N * 2);
    ushort_t* w1rb  = (ushort_t*)(ws + off); off = align256(off + (size_t)W1N * 2);
    ushort_t* w2b   = (ushort_t*)(ws + off); off = align256(off + (size_t)W2N * 2);

    hipMemsetAsync(deg_i, 0, (size_t)N * 4, stream);
    init_out_kernel<<<(out_size + 255) / 256, 256, 0, stream>>>(out, out_size);

    // CSR
    hist_kernel<<<(E + 255) / 256, 256, 0, stream>>>(dst, deg_i, E);
    chunk_sum_kernel<<<nb, 256, 0, stream>>>(deg_i, bsum, N);
    scan_bsum_kernel<<<1, 64, 0, stream>>>(bsum, bsum_ex, nb);
    write_rows_kernel<<<nb, 256, 0, stream>>>(deg_i, bsum_ex, row_start, cursor, N, E);
    place_kernel<<<(E + 255) / 256, 256, 0, stream>>>(src, dst, cursor, sorted_src, E);

    // conversions
    convert_kernel<<<(N * IN_F + 255) / 256, 256, 0, stream>>>(x, votes, xb, N);
    convertw_kernel<<<(W1N + W2N + 255) / 256, 256, 0, stream>>>(W1l, W1r, W2l, W2r,
                                                                 w1lb, w1rb, w2b);

    // layer 1 aggregate + both dense layers' matmuls (h1 stays in LDS)
    gather1_kernel<<<(N + 3) / 4, 256, 0, stream>>>(xb, row_start, sorted_src, agg1b, N);
    gemm1_kernel<<<(N + T1_M - 1) / T1_M, 256, 0, stream>>>(xb, agg1b, w1lb, w1rb, w2b,
                                                            b1, ub, vv, N);
    // layer 2 aggregate (64 dims, bf16)
    gatheru_kernel<<<(N + 3) / 4, 256, 0, stream>>>(ub, row_start, sorted_src, aggu, N);

    // h2 = aggu + v + b2, fused with segment-max
    finalize_kernel<<<(N + SEG_NODES - 1) / SEG_NODES, 256, 0, stream>>>(
        aggu, vv, b2, batch, out, N);
}

// Round 10
// 249.000 us; speedup vs baseline: 1.2845x; 1.2845x over previous
//
#include <hip/hip_runtime.h>
#include <hip/hip_bf16.h>

#define IN_F 108   // concat(x[107], votes[1])
#define XD   107
#define HID  128
#define OUTD 64
#define CHUNK 1024 // scan chunk per block
#define SEG_NODES 512
#define BP1_N (8 * 7 * 64 * 8)   // [ct][ks][lane][j] fragment-packed W1 (K=224 pad)
#define BP2_N (8 * 4 * 64 * 8)   // fragment-packed [W2l|W2r] (K=128)

typedef unsigned short ushort_t;
typedef unsigned int uint_t;
typedef __attribute__((ext_vector_type(8))) short bf16x8;
typedef __attribute__((ext_vector_type(4))) float f32x4;

__device__ inline void atomicMaxF(float* addr, float val) {
    if (val >= 0.f) atomicMax((int*)addr, __float_as_int(val));
    else            atomicMin((unsigned int*)addr, __float_as_uint(val));
}

__device__ inline ushort_t f2bf(float f) {
    uint_t b = __float_as_uint(f);
    return (ushort_t)((b + 0x7fffu + ((b >> 16) & 1u)) >> 16);   // RNE
}

__global__ void init_out_kernel(float* out, int n) {
    int i = blockIdx.x * 256 + threadIdx.x;
    if (i < n) out[i] = -__builtin_inff();
}

// ---- CSR build ----------------------------------------------------------
__global__ void hist_kernel(const int* __restrict__ dst, int* __restrict__ deg_i, int E) {
    int e = blockIdx.x * 256 + threadIdx.x;
    if (e < E) atomicAdd(&deg_i[dst[e]], 1);
}

__global__ __launch_bounds__(256) void chunk_sum_kernel(const int* __restrict__ deg_i,
                                                        int* __restrict__ bsum, int N) {
    int base = blockIdx.x * CHUNK;
    int v = 0;
    for (int i = threadIdx.x; i < CHUNK; i += 256) {
        int idx = base + i;
        if (idx < N) v += deg_i[idx];
    }
#pragma unroll
    for (int d = 1; d < 64; d <<= 1) v += __shfl_xor(v, d);
    __shared__ int red[4];
    int wid = threadIdx.x >> 6;
    if ((threadIdx.x & 63) == 0) red[wid] = v;
    __syncthreads();
    if (threadIdx.x == 0) bsum[blockIdx.x] = red[0] + red[1] + red[2] + red[3];
}

__global__ __launch_bounds__(64) void scan_bsum_kernel(const int* __restrict__ bsum,
                                                       int* __restrict__ bsum_ex, int nb) {
    int lane = threadIdx.x;
    int carry = 0;
    for (int b = 0; b < nb; b += 64) {
        int i = b + lane;
        int orig = (i < nb) ? bsum[i] : 0;
        int v = orig;
#pragma unroll
        for (int d = 1; d < 64; d <<= 1) {
            int t = __shfl_up(v, d);
            if (lane >= d) v += t;
        }
        if (i < nb) bsum_ex[i] = carry + v - orig;
        carry += __shfl(v, 63);
    }
}

__global__ __launch_bounds__(256) void write_rows_kernel(const int* __restrict__ deg_i,
                                                         const int* __restrict__ bsum_ex,
                                                         int* __restrict__ row_start,
                                                         int* __restrict__ cursor,
                                                         int N, int E) {
    __shared__ int s[256];
    int base = blockIdx.x * CHUNK;
    int i0 = base + threadIdx.x * 4;
    int d0 = 0, d1 = 0, d2 = 0, d3 = 0;
    if (i0 + 3 < N) {
        int4 q = *(const int4*)(deg_i + i0);
        d0 = q.x; d1 = q.y; d2 = q.z; d3 = q.w;
    } else {
        if (i0 + 0 < N) d0 = deg_i[i0 + 0];
        if (i0 + 1 < N) d1 = deg_i[i0 + 1];
        if (i0 + 2 < N) d2 = deg_i[i0 + 2];
        if (i0 + 3 < N) d3 = deg_i[i0 + 3];
    }
    int tsum = d0 + d1 + d2 + d3;
    s[threadIdx.x] = tsum;
    __syncthreads();
    for (int d = 1; d < 256; d <<= 1) {
        int t = (threadIdx.x >= d) ? s[threadIdx.x - d] : 0;
        __syncthreads();
        s[threadIdx.x] += t;
        __syncthreads();
    }
    int off = bsum_ex[blockIdx.x] + s[threadIdx.x] - tsum;
    if (i0 + 0 < N) { row_start[i0 + 0] = off; cursor[i0 + 0] = off; off += d0; }
    if (i0 + 1 < N) { row_start[i0 + 1] = off; cursor[i0 + 1] = off; off += d1; }
    if (i0 + 2 < N) { row_start[i0 + 2] = off; cursor[i0 + 2] = off; off += d2; }
    if (i0 + 3 < N) { row_start[i0 + 3] = off; cursor[i0 + 3] = off; off += d3; }
    if (blockIdx.x == 0 && threadIdx.x == 0) row_start[N] = E;
}

__global__ void place_kernel(const int* __restrict__ src, const int* __restrict__ dst,
                             int* __restrict__ cursor, int* __restrict__ sorted_src, int E) {
    int e = blockIdx.x * 256 + threadIdx.x;
    if (e >= E) return;
    int pos = atomicAdd(&cursor[dst[e]], 1);
    sorted_src[pos] = src[e];
}

// ---- bf16 copy of h0 ----------------------------------------------------
__global__ void convert_kernel(const float* __restrict__ x, const float* __restrict__ votes,
                               ushort_t* __restrict__ xb, int N) {
    int idx = blockIdx.x * 256 + threadIdx.x;
    if (idx >= N * IN_F) return;
    int n = idx / IN_F, f = idx - n * IN_F;
    float v = (f < XD) ? x[n * XD + f] : votes[n];
    xb[idx] = f2bf(v);
}

// ---- weights -> MFMA-fragment-packed bf16 (once per launch) -------------
// bp1: W1=[W1l;W1r] K=216 pad 224. idx = ((ct*7+ks)*64+lane)*8+j
//      element = W1[ks*32+(lane>>4)*8+j][ct*16+(lane&15)]
// bp2: W2=[W2l|W2r] K=128.         idx = ((ct*4+ks)*64+lane)*8+j
__global__ void convertw_kernel(const float* __restrict__ W1l, const float* __restrict__ W1r,
                                const float* __restrict__ W2l, const float* __restrict__ W2r,
                                ushort_t* __restrict__ bp1, ushort_t* __restrict__ bp2) {
    int i = blockIdx.x * 256 + threadIdx.x;
    if (i < BP1_N) {
        int j = i & 7;
        int lane = (i >> 3) & 63;
        int rest = i >> 9;
        int ks = rest % 7;
        int ct = rest / 7;
        int k = ks * 32 + (lane >> 4) * 8 + j;
        int col = ct * 16 + (lane & 15);
        float v = 0.f;
        if (k < IN_F) v = W1l[k * HID + col];
        else if (k < 2 * IN_F) v = W1r[(k - IN_F) * HID + col];
        bp1[i] = f2bf(v);
    }
    int i2 = i - BP1_N;
    if (i2 >= 0 && i2 < BP2_N) {
        int j = i2 & 7;
        int lane = (i2 >> 3) & 63;
        int ks = (i2 >> 9) & 3;
        int ct = i2 >> 11;
        int k = ks * 32 + (lane >> 4) * 8 + j;
        int col = ct * 16 + (lane & 15);
        float v = (col < OUTD) ? W2l[k * OUTD + col] : W2r[k * OUTD + (col - OUTD)];
        bp2[i2] = f2bf(v);
    }
}

// ---- gather-mean layer 1 (bf16 in, f32 accum, bf16 out, pre-divided) ----
__global__ __launch_bounds__(256) void gather1_kernel(
        const ushort_t* __restrict__ xb,
        const int* __restrict__ row_start, const int* __restrict__ sorted_src,
        ushort_t* __restrict__ agg1b, int N) {
    int node = (blockIdx.x * 256 + threadIdx.x) >> 6;
    int lane = threadIdx.x & 63;
    if (node >= N) return;
    int rs = row_start[node], re = row_start[node + 1];
    int h  = lane >> 5;
    int l2 = lane & 31;
    float a0 = 0.f, a1 = 0.f, a2 = 0.f, a3 = 0.f;
    for (int k0 = rs; k0 < re; k0 += 64) {
        int cnt = min(64, re - k0);
        int sl = sorted_src[k0 + min(lane, cnt - 1)];
        for (int t = 0; t < cnt; t += 2) {
            int tt = min(t + h, cnt - 1);
            int s = __shfl(sl, tt);
            if (t + h < cnt && l2 < 27) {
                uint2 w = *(const uint2*)(xb + s * IN_F + 4 * l2);
                a0 += __uint_as_float(w.x << 16);
                a1 += __uint_as_float(w.x & 0xffff0000u);
                a2 += __uint_as_float(w.y << 16);
                a3 += __uint_as_float(w.y & 0xffff0000u);
            }
        }
    }
    a0 += __shfl_xor(a0, 32);
    a1 += __shfl_xor(a1, 32);
    a2 += __shfl_xor(a2, 32);
    a3 += __shfl_xor(a3, 32);
    float inv = 1.f / fmaxf((float)(re - rs), 1.f);
    if (lane < 27) {
        ushort4 p;
        p.x = f2bf(a0 * inv);
        p.y = f2bf(a1 * inv);
        p.z = f2bf(a2 * inv);
        p.w = f2bf(a3 * inv);
        *(ushort4*)(agg1b + node * IN_F + 4 * lane) = p;
    }
}

// ---- gather-mean of u (bf16, 64 dims) -----------------------------------
__global__ __launch_bounds__(256) void gatheru_kernel(
        const ushort_t* __restrict__ ub,
        const int* __restrict__ row_start, const int* __restrict__ sorted_src,
        float* __restrict__ aggu, int N) {
    int node = (blockIdx.x * 256 + threadIdx.x) >> 6;
    int lane = threadIdx.x & 63;
    if (node >= N) return;
    int rs = row_start[node], re = row_start[node + 1];
    int g  = lane >> 4;
    int l4 = lane & 15;
    float a0 = 0.f, a1 = 0.f, a2 = 0.f, a3 = 0.f;
    for (int k0 = rs; k0 < re; k0 += 64) {
        int cnt = min(64, re - k0);
        int sl = sorted_src[k0 + min(lane, cnt - 1)];
        for (int t = 0; t < cnt; t += 4) {
            int tt = min(t + g, cnt - 1);
            int s = __shfl(sl, tt);
            if (t + g < cnt) {
                uint2 w = *(const uint2*)(ub + (s << 6) + 4 * l4);
                a0 += __uint_as_float(w.x << 16);
                a1 += __uint_as_float(w.x & 0xffff0000u);
                a2 += __uint_as_float(w.y << 16);
                a3 += __uint_as_float(w.y & 0xffff0000u);
            }
        }
    }
    a0 += __shfl_xor(a0, 16); a0 += __shfl_xor(a0, 32);
    a1 += __shfl_xor(a1, 16); a1 += __shfl_xor(a1, 32);
    a2 += __shfl_xor(a2, 16); a2 += __shfl_xor(a2, 32);
    a3 += __shfl_xor(a3, 16); a3 += __shfl_xor(a3, 32);
    float inv = 1.f / fmaxf((float)(re - rs), 1.f);
    if (lane < 16) {
        *(float4*)(aggu + (node << 6) + 4 * lane) =
            make_float4(a0 * inv, a1 * inv, a2 * inv, a3 * inv);
    }
}

// ---- MFMA fused dense ----------------------------------------------------
// h1 = relu([agg|h0] @ [W1l;W1r] + b1);  [u|v] = h1 @ [W2l|W2r]
// Block: 4 waves, 32 nodes x 128 cols; wave = 16 rows x 64 cols (4 frags).
// A staged bf16 in LDS (row stride 232 us); h1 bf16 in LDS (stride 136 us).
#define T1_M 32
#define A_STRIDE_US 232   // 464 B/row: 16B-aligned, 2-way-free bank spread
#define A_STRIDE_U  116
#define H1_STRIDE_US 136  // 272 B/row
__global__ __launch_bounds__(256) void gemm1_kernel(
        const ushort_t* __restrict__ xb, const ushort_t* __restrict__ agg1b,
        const ushort_t* __restrict__ bp1, const ushort_t* __restrict__ bp2,
        const float* __restrict__ b1,
        ushort_t* __restrict__ ub, float* __restrict__ vv, int N) {
    __shared__ uint_t smem[T1_M * A_STRIDE_U];      // 14848 B
    int n0 = blockIdx.x * T1_M;
    // stage A: per row 112 uints: [0,54)=agg, [54,108)=h0, [108,112)=zero pad
    for (int i = threadIdx.x; i < T1_M * 112; i += 256) {
        int m = i / 112, c = i - m * 112;
        int n = n0 + m;
        uint_t v = 0u;
        if (n < N) {
            if (c < 54)       v = ((const uint_t*)(agg1b + n * IN_F))[c];
            else if (c < 108) v = ((const uint_t*)(xb + n * IN_F))[c - 54];
        }
        smem[m * A_STRIDE_U + c] = v;
    }
    __syncthreads();

    int lane = threadIdx.x & 63;
    int wid  = threadIdx.x >> 6;
    int wrow = (wid & 1) << 4;          // 0 / 16
    int wcol = (wid >> 1) << 6;         // 0 / 64
    int arow = wrow + (lane & 15);
    int akoff = (lane >> 4) * 8;
    const ushort_t* sA = (const ushort_t*)smem;
    const bf16x8* bp1v = (const bf16x8*)bp1;

    f32x4 acc0 = {}, acc1 = {}, acc2_ = {}, acc3 = {};
    int ct0 = wcol >> 4;
#pragma unroll
    for (int ks = 0; ks < 7; ++ks) {
        bf16x8 af = *(const bf16x8*)(sA + arow * A_STRIDE_US + ks * 32 + akoff);
        bf16x8 bf0 = bp1v[((ct0 + 0) * 7 + ks) * 64 + lane];
        bf16x8 bf1 = bp1v[((ct0 + 1) * 7 + ks) * 64 + lane];
        bf16x8 bf2 = bp1v[((ct0 + 2) * 7 + ks) * 64 + lane];
        bf16x8 bf3 = bp1v[((ct0 + 3) * 7 + ks) * 64 + lane];
        acc0 = __builtin_amdgcn_mfma_f32_16x16x32_bf16(af, bf0, acc0, 0, 0, 0);
        acc1 = __builtin_amdgcn_mfma_f32_16x16x32_bf16(af, bf1, acc1, 0, 0, 0);
        acc2_ = __builtin_amdgcn_mfma_f32_16x16x32_bf16(af, bf2, acc2_, 0, 0, 0);
        acc3 = __builtin_amdgcn_mfma_f32_16x16x32_bf16(af, bf3, acc3, 0, 0, 0);
    }

    // bias + relu -> h1 (bf16) in LDS
    __syncthreads();
    ushort_t* sh1 = (ushort_t*)smem;
    {
        int colb = wcol + (lane & 15);
        int rowb = wrow + ((lane >> 4) << 2);
#pragma unroll
        for (int t = 0; t < 4; ++t) {
            f32x4 a = (t == 0) ? acc0 : (t == 1) ? acc1 : (t == 2) ? acc2_ : acc3;
            int col = colb + t * 16;
            float bj = b1[col];
#pragma unroll
            for (int r = 0; r < 4; ++r)
                sh1[(rowb + r) * H1_STRIDE_US + col] = f2bf(fmaxf(a[r] + bj, 0.f));
        }
    }
    __syncthreads();

    const bf16x8* bp2v = (const bf16x8*)bp2;
    f32x4 dcc0 = {}, dcc1 = {}, dcc2 = {}, dcc3 = {};
#pragma unroll
    for (int ks = 0; ks < 4; ++ks) {
        bf16x8 af = *(const bf16x8*)(sh1 + arow * H1_STRIDE_US + ks * 32 + akoff);
        bf16x8 bf0 = bp2v[((ct0 + 0) * 4 + ks) * 64 + lane];
        bf16x8 bf1 = bp2v[((ct0 + 1) * 4 + ks) * 64 + lane];
        bf16x8 bf2 = bp2v[((ct0 + 2) * 4 + ks) * 64 + lane];
        bf16x8 bf3 = bp2v[((ct0 + 3) * 4 + ks) * 64 + lane];
        dcc0 = __builtin_amdgcn_mfma_f32_16x16x32_bf16(af, bf0, dcc0, 0, 0, 0);
        dcc1 = __builtin_amdgcn_mfma_f32_16x16x32_bf16(af, bf1, dcc1, 0, 0, 0);
        dcc2 = __builtin_amdgcn_mfma_f32_16x16x32_bf16(af, bf2, dcc2, 0, 0, 0);
        dcc3 = __builtin_amdgcn_mfma_f32_16x16x32_bf16(af, bf3, dcc3, 0, 0, 0);
    }

    {
        int colb = wcol + (lane & 15);
        int rowb = wrow + ((lane >> 4) << 2);
#pragma unroll
        for (int t = 0; t < 4; ++t) {
            f32x4 a = (t == 0) ? dcc0 : (t == 1) ? dcc1 : (t == 2) ? dcc2 : dcc3;
            int col = colb + t * 16;
#pragma unroll
            for (int r = 0; r < 4; ++r) {
                int n = n0 + rowb + r;
                if (n < N) {
                    if (col < OUTD) ub[(n << 6) + col] = f2bf(a[r]);
                    else            vv[(n << 6) + (col - OUTD)] = a[r];
                }
            }
        }
    }
}

// ---- finalize: h2 = aggu + v + b2, then run-length segment-max ----------
__global__ __launch_bounds__(256) void finalize_kernel(
        const float* __restrict__ aggu, const float* __restrict__ vv,
        const float* __restrict__ b2, const int* __restrict__ batch,
        float* __restrict__ out, int N) {
    int j  = threadIdx.x & 63;
    int nq = threadIdx.x >> 6;
    int n0 = blockIdx.x * SEG_NODES;
    float bj = b2[j];
    int curg = -1;
    float curm = -__builtin_inff();
    for (int m = nq; m < SEG_NODES; m += 4) {
        int n = n0 + m;
        if (n >= N) break;
        int g = batch[n];
        float v = aggu[(n << 6) + j] + vv[(n << 6) + j] + bj;
        if (g != curg) {
            if (curg >= 0) atomicMaxF(&out[(curg << 6) + j], curm);
            curg = g;
            curm = v;
        } else {
            curm = fmaxf(curm, v);
        }
    }
    if (curg >= 0) atomicMaxF(&out[(curg << 6) + j], curm);
}

static inline size_t align256(size_t v) { return (v + 255) & ~(size_t)255; }

extern "C" void kernel_launch(void* const* d_in, const int* in_sizes, int n_in,
                              void* d_out, int out_size, void* d_ws, size_t ws_size,
                              hipStream_t stream) {
    const float* x     = (const float*)d_in[0];
    const float* votes = (const float*)d_in[1];
    const int*   eidx  = (const int*)d_in[2];
    const int*   batch = (const int*)d_in[3];
    const float* W1l   = (const float*)d_in[4];
    const float* b1    = (const float*)d_in[5];
    const float* W1r   = (const float*)d_in[6];
    const float* W2l   = (const float*)d_in[7];
    const float* b2    = (const float*)d_in[8];
    const float* W2r   = (const float*)d_in[9];
    float* out = (float*)d_out;

    const int N = in_sizes[1];
    const int E = in_sizes[2] / 2;
    const int* src = eidx;
    const int* dst = eidx + E;
    const int nb = (N + CHUNK - 1) / CHUNK;

    char* ws = (char*)d_ws;
    size_t off = 0;
    int* deg_i      = (int*)(ws + off); off = align256(off + (size_t)N * 4);
    int* row_start  = (int*)(ws + off); off = align256(off + (size_t)(N + 1) * 4);
    int* cursor     = (int*)(ws + off); off = align256(off + (size_t)N * 4);
    int* bsum       = (int*)(ws + off); off = align256(off + (size_t)nb * 4);
    int* bsum_ex    = (int*)(ws + off); off = align256(off + (size_t)nb * 4);
    int* sorted_src = (int*)(ws + off); off = align256(off + (size_t)E * 4);
    ushort_t* xb    = (ushort_t*)(ws + off); off = align256(off + (size_t)N * IN_F * 2);
    ushort_t* agg1b = (ushort_t*)(ws + off); off = align256(off + (size_t)N * IN_F * 2);
    ushort_t* ub    = (ushort_t*)(ws + off); off = align256(off + (size_t)N * OUTD * 2);
    float* vv       = (float*)(ws + off); off = align256(off + (size_t)N * OUTD * 4);
    float* aggu     = (float*)(ws + off); off = align256(off + (size_t)N * OUTD * 4);
    ushort_t* bp1   = (ushort_t*)(ws + off); off = align256(off + (size_t)BP1_N * 2);
    ushort_t* bp2   = (ushort_t*)(ws + off); off = align256(off + (size_t)BP2_N * 2);

    hipMemsetAsync(deg_i, 0, (size_t)N * 4, stream);
    init_out_kernel<<<(out_size + 255) / 256, 256, 0, stream>>>(out, out_size);

    // CSR
    hist_kernel<<<(E + 255) / 256, 256, 0, stream>>>(dst, deg_i, E);
    chunk_sum_kernel<<<nb, 256, 0, stream>>>(deg_i, bsum, N);
    scan_bsum_kernel<<<1, 64, 0, stream>>>(bsum, bsum_ex, nb);
    write_rows_kernel<<<nb, 256, 0, stream>>>(deg_i, bsum_ex, row_start, cursor, N, E);
    place_kernel<<<(E + 255) / 256, 256, 0, stream>>>(src, dst, cursor, sorted_src, E);

    // conversions (xb; fragment-packed weights)
    convert_kernel<<<(N * IN_F + 255) / 256, 256, 0, stream>>>(x, votes, xb, N);
    convertw_kernel<<<(BP1_N + BP2_N + 255) / 256, 256, 0, stream>>>(W1l, W1r, W2l, W2r,
                                                                     bp1, bp2);

    // layer 1 aggregate + both dense matmuls via MFMA (h1 stays in LDS)
    gather1_kernel<<<(N + 3) / 4, 256, 0, stream>>>(xb, row_start, sorted_src, agg1b, N);
    gemm1_kernel<<<(N + T1_M - 1) / T1_M, 256, 0, stream>>>(xb, agg1b, bp1, bp2,
                                                            b1, ub, vv, N);
    // layer 2 aggregate (64 dims, bf16)
    gatheru_kernel<<<(N + 3) / 4, 256, 0, stream>>>(ub, row_start, sorted_src, aggu, N);

    // h2 = aggu + v + b2, fused with segment-max
    finalize_kernel<<<(N + SEG_NODES - 1) / SEG_NODES, 256, 0, stream>>>(
        aggu, vv, b2, batch, out, N);
}

// Round 11
// 210.492 us; speedup vs baseline: 1.5195x; 1.1829x over previous
//
#include <hip/hip_runtime.h>
#include <hip/hip_bf16.h>

#define IN_F 108   // concat(x[107], votes[1])
#define XD   107
#define HID  128
#define OUTD 64
#define CHUNK 1024 // scan chunk per block
#define SEG_NODES 64
#define BP1_N (8 * 7 * 64 * 8)   // [ct][ks][lane][j] fragment-packed W1 (K=224 pad)
#define BP2_N (8 * 4 * 64 * 8)   // fragment-packed [W2l|W2r] (K=128)

typedef unsigned short ushort_t;
typedef unsigned int uint_t;
typedef __attribute__((ext_vector_type(8))) short bf16x8;
typedef __attribute__((ext_vector_type(4))) float f32x4;

__device__ inline void atomicMaxF(float* addr, float val) {
    if (val >= 0.f) atomicMax((int*)addr, __float_as_int(val));
    else            atomicMin((unsigned int*)addr, __float_as_uint(val));
}

__device__ inline ushort_t f2bf(float f) {
    uint_t b = __float_as_uint(f);
    return (ushort_t)((b + 0x7fffu + ((b >> 16) & 1u)) >> 16);   // RNE
}

__global__ void init_out_kernel(float* out, int n) {
    int i = blockIdx.x * 256 + threadIdx.x;
    if (i < n) out[i] = -__builtin_inff();
}

// ---- CSR build ----------------------------------------------------------
// 2 edges per thread (int2 loads) for atomic-latency overlap
__global__ __launch_bounds__(256) void hist_kernel(const int* __restrict__ dst,
                                                   int* __restrict__ deg_i, int E2) {
    int e2 = blockIdx.x * 256 + threadIdx.x;
    if (e2 >= E2) return;
    int2 d = ((const int2*)dst)[e2];
    atomicAdd(&deg_i[d.x], 1);
    atomicAdd(&deg_i[d.y], 1);
}

__global__ __launch_bounds__(256) void chunk_sum_kernel(const int* __restrict__ deg_i,
                                                        int* __restrict__ bsum, int N) {
    int base = blockIdx.x * CHUNK;
    int v = 0;
    for (int i = threadIdx.x; i < CHUNK; i += 256) {
        int idx = base + i;
        if (idx < N) v += deg_i[idx];
    }
#pragma unroll
    for (int d = 1; d < 64; d <<= 1) v += __shfl_xor(v, d);
    __shared__ int red[4];
    int wid = threadIdx.x >> 6;
    if ((threadIdx.x & 63) == 0) red[wid] = v;
    __syncthreads();
    if (threadIdx.x == 0) bsum[blockIdx.x] = red[0] + red[1] + red[2] + red[3];
}

__global__ __launch_bounds__(64) void scan_bsum_kernel(const int* __restrict__ bsum,
                                                       int* __restrict__ bsum_ex, int nb) {
    int lane = threadIdx.x;
    int carry = 0;
    for (int b = 0; b < nb; b += 64) {
        int i = b + lane;
        int orig = (i < nb) ? bsum[i] : 0;
        int v = orig;
#pragma unroll
        for (int d = 1; d < 64; d <<= 1) {
            int t = __shfl_up(v, d);
            if (lane >= d) v += t;
        }
        if (i < nb) bsum_ex[i] = carry + v - orig;
        carry += __shfl(v, 63);
    }
}

__global__ __launch_bounds__(256) void write_rows_kernel(const int* __restrict__ deg_i,
                                                         const int* __restrict__ bsum_ex,
                                                         int* __restrict__ row_start,
                                                         int* __restrict__ cursor,
                                                         int N, int E) {
    __shared__ int s[256];
    int base = blockIdx.x * CHUNK;
    int i0 = base + threadIdx.x * 4;
    int d0 = 0, d1 = 0, d2 = 0, d3 = 0;
    if (i0 + 3 < N) {
        int4 q = *(const int4*)(deg_i + i0);
        d0 = q.x; d1 = q.y; d2 = q.z; d3 = q.w;
    } else {
        if (i0 + 0 < N) d0 = deg_i[i0 + 0];
        if (i0 + 1 < N) d1 = deg_i[i0 + 1];
        if (i0 + 2 < N) d2 = deg_i[i0 + 2];
        if (i0 + 3 < N) d3 = deg_i[i0 + 3];
    }
    int tsum = d0 + d1 + d2 + d3;
    s[threadIdx.x] = tsum;
    __syncthreads();
    for (int d = 1; d < 256; d <<= 1) {
        int t = (threadIdx.x >= d) ? s[threadIdx.x - d] : 0;
        __syncthreads();
        s[threadIdx.x] += t;
        __syncthreads();
    }
    int off = bsum_ex[blockIdx.x] + s[threadIdx.x] - tsum;
    if (i0 + 0 < N) { row_start[i0 + 0] = off; cursor[i0 + 0] = off; off += d0; }
    if (i0 + 1 < N) { row_start[i0 + 1] = off; cursor[i0 + 1] = off; off += d1; }
    if (i0 + 2 < N) { row_start[i0 + 2] = off; cursor[i0 + 2] = off; off += d2; }
    if (i0 + 3 < N) { row_start[i0 + 3] = off; cursor[i0 + 3] = off; off += d3; }
    if (blockIdx.x == 0 && threadIdx.x == 0) row_start[N] = E;
}

__global__ __launch_bounds__(256) void place_kernel(const int* __restrict__ src,
                                                    const int* __restrict__ dst,
                                                    int* __restrict__ cursor,
                                                    int* __restrict__ sorted_src, int E2) {
    int e2 = blockIdx.x * 256 + threadIdx.x;
    if (e2 >= E2) return;
    int2 s = ((const int2*)src)[e2];
    int2 d = ((const int2*)dst)[e2];
    int p0 = atomicAdd(&cursor[d.x], 1);
    int p1 = atomicAdd(&cursor[d.y], 1);
    sorted_src[p0] = s.x;
    sorted_src[p1] = s.y;
}

// ---- bf16 copy of h0 ----------------------------------------------------
__global__ void convert_kernel(const float* __restrict__ x, const float* __restrict__ votes,
                               ushort_t* __restrict__ xb, int N) {
    int idx = blockIdx.x * 256 + threadIdx.x;
    if (idx >= N * IN_F) return;
    int n = idx / IN_F, f = idx - n * IN_F;
    float v = (f < XD) ? x[n * XD + f] : votes[n];
    xb[idx] = f2bf(v);
}

// ---- weights -> MFMA-fragment-packed bf16 (once per launch) -------------
__global__ void convertw_kernel(const float* __restrict__ W1l, const float* __restrict__ W1r,
                                const float* __restrict__ W2l, const float* __restrict__ W2r,
                                ushort_t* __restrict__ bp1, ushort_t* __restrict__ bp2) {
    int i = blockIdx.x * 256 + threadIdx.x;
    if (i < BP1_N) {
        int j = i & 7;
        int lane = (i >> 3) & 63;
        int rest = i >> 9;
        int ks = rest % 7;
        int ct = rest / 7;
        int k = ks * 32 + (lane >> 4) * 8 + j;
        int col = ct * 16 + (lane & 15);
        float v = 0.f;
        if (k < IN_F) v = W1l[k * HID + col];
        else if (k < 2 * IN_F) v = W1r[(k - IN_F) * HID + col];
        bp1[i] = f2bf(v);
    }
    int i2 = i - BP1_N;
    if (i2 >= 0 && i2 < BP2_N) {
        int j = i2 & 7;
        int lane = (i2 >> 3) & 63;
        int ks = (i2 >> 9) & 3;
        int ct = i2 >> 11;
        int k = ks * 32 + (lane >> 4) * 8 + j;
        int col = ct * 16 + (lane & 15);
        float v = (col < OUTD) ? W2l[k * OUTD + col] : W2r[k * OUTD + (col - OUTD)];
        bp2[i2] = f2bf(v);
    }
}

// ---- gather-mean layer 1 (bf16 in, f32 accum, bf16 out, pre-divided) ----
__global__ __launch_bounds__(256) void gather1_kernel(
        const ushort_t* __restrict__ xb,
        const int* __restrict__ row_start, const int* __restrict__ sorted_src,
        ushort_t* __restrict__ agg1b, int N) {
    int node = (blockIdx.x * 256 + threadIdx.x) >> 6;
    int lane = threadIdx.x & 63;
    if (node >= N) return;
    int rs = row_start[node], re = row_start[node + 1];
    int h  = lane >> 5;
    int l2 = lane & 31;
    float a0 = 0.f, a1 = 0.f, a2 = 0.f, a3 = 0.f;
    for (int k0 = rs; k0 < re; k0 += 64) {
        int cnt = min(64, re - k0);
        int sl = sorted_src[k0 + min(lane, cnt - 1)];
        for (int t = 0; t < cnt; t += 2) {
            int tt = min(t + h, cnt - 1);
            int s = __shfl(sl, tt);
            if (t + h < cnt && l2 < 27) {
                uint2 w = *(const uint2*)(xb + s * IN_F + 4 * l2);
                a0 += __uint_as_float(w.x << 16);
                a1 += __uint_as_float(w.x & 0xffff0000u);
                a2 += __uint_as_float(w.y << 16);
                a3 += __uint_as_float(w.y & 0xffff0000u);
            }
        }
    }
    a0 += __shfl_xor(a0, 32);
    a1 += __shfl_xor(a1, 32);
    a2 += __shfl_xor(a2, 32);
    a3 += __shfl_xor(a3, 32);
    float inv = 1.f / fmaxf((float)(re - rs), 1.f);
    if (lane < 27) {
        ushort4 p;
        p.x = f2bf(a0 * inv);
        p.y = f2bf(a1 * inv);
        p.z = f2bf(a2 * inv);
        p.w = f2bf(a3 * inv);
        *(ushort4*)(agg1b + node * IN_F + 4 * lane) = p;
    }
}

// ---- gather-mean of u (bf16, 64 dims) -----------------------------------
__global__ __launch_bounds__(256) void gatheru_kernel(
        const ushort_t* __restrict__ ub,
        const int* __restrict__ row_start, const int* __restrict__ sorted_src,
        float* __restrict__ aggu, int N) {
    int node = (blockIdx.x * 256 + threadIdx.x) >> 6;
    int lane = threadIdx.x & 63;
    if (node >= N) return;
    int rs = row_start[node], re = row_start[node + 1];
    int g  = lane >> 4;
    int l4 = lane & 15;
    float a0 = 0.f, a1 = 0.f, a2 = 0.f, a3 = 0.f;
    for (int k0 = rs; k0 < re; k0 += 64) {
        int cnt = min(64, re - k0);
        int sl = sorted_src[k0 + min(lane, cnt - 1)];
        for (int t = 0; t < cnt; t += 4) {
            int tt = min(t + g, cnt - 1);
            int s = __shfl(sl, tt);
            if (t + g < cnt) {
                uint2 w = *(const uint2*)(ub + (s << 6) + 4 * l4);
                a0 += __uint_as_float(w.x << 16);
                a1 += __uint_as_float(w.x & 0xffff0000u);
                a2 += __uint_as_float(w.y << 16);
                a3 += __uint_as_float(w.y & 0xffff0000u);
            }
        }
    }
    a0 += __shfl_xor(a0, 16); a0 += __shfl_xor(a0, 32);
    a1 += __shfl_xor(a1, 16); a1 += __shfl_xor(a1, 32);
    a2 += __shfl_xor(a2, 16); a2 += __shfl_xor(a2, 32);
    a3 += __shfl_xor(a3, 16); a3 += __shfl_xor(a3, 32);
    float inv = 1.f / fmaxf((float)(re - rs), 1.f);
    if (lane < 16) {
        *(float4*)(aggu + (node << 6) + 4 * lane) =
            make_float4(a0 * inv, a1 * inv, a2 * inv, a3 * inv);
    }
}

// ---- MFMA fused dense ----------------------------------------------------
#define T1_M 32
#define A_STRIDE_US 232
#define A_STRIDE_U  116
#define H1_STRIDE_US 136
__global__ __launch_bounds__(256) void gemm1_kernel(
        const ushort_t* __restrict__ xb, const ushort_t* __restrict__ agg1b,
        const ushort_t* __restrict__ bp1, const ushort_t* __restrict__ bp2,
        const float* __restrict__ b1,
        ushort_t* __restrict__ ub, float* __restrict__ vv, int N) {
    __shared__ uint_t smem[T1_M * A_STRIDE_U];      // 14848 B
    int n0 = blockIdx.x * T1_M;
    for (int i = threadIdx.x; i < T1_M * 112; i += 256) {
        int m = i / 112, c = i - m * 112;
        int n = n0 + m;
        uint_t v = 0u;
        if (n < N) {
            if (c < 54)       v = ((const uint_t*)(agg1b + n * IN_F))[c];
            else if (c < 108) v = ((const uint_t*)(xb + n * IN_F))[c - 54];
        }
        smem[m * A_STRIDE_U + c] = v;
    }
    __syncthreads();

    int lane = threadIdx.x & 63;
    int wid  = threadIdx.x >> 6;
    int wrow = (wid & 1) << 4;
    int wcol = (wid >> 1) << 6;
    int arow = wrow + (lane & 15);
    int akoff = (lane >> 4) * 8;
    const ushort_t* sA = (const ushort_t*)smem;
    const bf16x8* bp1v = (const bf16x8*)bp1;

    f32x4 acc0 = {}, acc1 = {}, acc2_ = {}, acc3 = {};
    int ct0 = wcol >> 4;
#pragma unroll
    for (int ks = 0; ks < 7; ++ks) {
        bf16x8 af = *(const bf16x8*)(sA + arow * A_STRIDE_US + ks * 32 + akoff);
        bf16x8 bf0 = bp1v[((ct0 + 0) * 7 + ks) * 64 + lane];
        bf16x8 bf1 = bp1v[((ct0 + 1) * 7 + ks) * 64 + lane];
        bf16x8 bf2 = bp1v[((ct0 + 2) * 7 + ks) * 64 + lane];
        bf16x8 bf3 = bp1v[((ct0 + 3) * 7 + ks) * 64 + lane];
        acc0 = __builtin_amdgcn_mfma_f32_16x16x32_bf16(af, bf0, acc0, 0, 0, 0);
        acc1 = __builtin_amdgcn_mfma_f32_16x16x32_bf16(af, bf1, acc1, 0, 0, 0);
        acc2_ = __builtin_amdgcn_mfma_f32_16x16x32_bf16(af, bf2, acc2_, 0, 0, 0);
        acc3 = __builtin_amdgcn_mfma_f32_16x16x32_bf16(af, bf3, acc3, 0, 0, 0);
    }

    __syncthreads();
    ushort_t* sh1 = (ushort_t*)smem;
    {
        int colb = wcol + (lane & 15);
        int rowb = wrow + ((lane >> 4) << 2);
#pragma unroll
        for (int t = 0; t < 4; ++t) {
            f32x4 a = (t == 0) ? acc0 : (t == 1) ? acc1 : (t == 2) ? acc2_ : acc3;
            int col = colb + t * 16;
            float bj = b1[col];
#pragma unroll
            for (int r = 0; r < 4; ++r)
                sh1[(rowb + r) * H1_STRIDE_US + col] = f2bf(fmaxf(a[r] + bj, 0.f));
        }
    }
    __syncthreads();

    const bf16x8* bp2v = (const bf16x8*)bp2;
    f32x4 dcc0 = {}, dcc1 = {}, dcc2 = {}, dcc3 = {};
#pragma unroll
    for (int ks = 0; ks < 4; ++ks) {
        bf16x8 af = *(const bf16x8*)(sh1 + arow * H1_STRIDE_US + ks * 32 + akoff);
        bf16x8 bf0 = bp2v[((ct0 + 0) * 4 + ks) * 64 + lane];
        bf16x8 bf1 = bp2v[((ct0 + 1) * 4 + ks) * 64 + lane];
        bf16x8 bf2 = bp2v[((ct0 + 2) * 4 + ks) * 64 + lane];
        bf16x8 bf3 = bp2v[((ct0 + 3) * 4 + ks) * 64 + lane];
        dcc0 = __builtin_amdgcn_mfma_f32_16x16x32_bf16(af, bf0, dcc0, 0, 0, 0);
        dcc1 = __builtin_amdgcn_mfma_f32_16x16x32_bf16(af, bf1, dcc1, 0, 0, 0);
        dcc2 = __builtin_amdgcn_mfma_f32_16x16x32_bf16(af, bf2, dcc2, 0, 0, 0);
        dcc3 = __builtin_amdgcn_mfma_f32_16x16x32_bf16(af, bf3, dcc3, 0, 0, 0);
    }

    {
        int colb = wcol + (lane & 15);
        int rowb = wrow + ((lane >> 4) << 2);
#pragma unroll
        for (int t = 0; t < 4; ++t) {
            f32x4 a = (t == 0) ? dcc0 : (t == 1) ? dcc1 : (t == 2) ? dcc2 : dcc3;
            int col = colb + t * 16;
#pragma unroll
            for (int r = 0; r < 4; ++r) {
                int n = n0 + rowb + r;
                if (n < N) {
                    if (col < OUTD) ub[(n << 6) + col] = f2bf(a[r]);
                    else            vv[(n << 6) + (col - OUTD)] = a[r];
                }
            }
        }
    }
}

// ---- finalize: h2 = aggu + v + b2, then run-length segment-max ----------
// SEG_NODES=64 -> 782 blocks (latency hidden by TLP); each thread walks 16 nodes
__global__ __launch_bounds__(256) void finalize_kernel(
        const float* __restrict__ aggu, const float* __restrict__ vv,
        const float* __restrict__ b2, const int* __restrict__ batch,
        float* __restrict__ out, int N) {
    int j  = threadIdx.x & 63;
    int nq = threadIdx.x >> 6;
    int n0 = blockIdx.x * SEG_NODES;
    float bj = b2[j];
    int curg = -1;
    float curm = -__builtin_inff();
    for (int m = nq; m < SEG_NODES; m += 4) {
        int n = n0 + m;
        if (n >= N) break;
        int g = batch[n];
        float v = aggu[(n << 6) + j] + vv[(n << 6) + j] + bj;
        if (g != curg) {
            if (curg >= 0) atomicMaxF(&out[(curg << 6) + j], curm);
            curg = g;
            curm = v;
        } else {
            curm = fmaxf(curm, v);
        }
    }
    if (curg >= 0) atomicMaxF(&out[(curg << 6) + j], curm);
}

static inline size_t align256(size_t v) { return (v + 255) & ~(size_t)255; }

extern "C" void kernel_launch(void* const* d_in, const int* in_sizes, int n_in,
                              void* d_out, int out_size, void* d_ws, size_t ws_size,
                              hipStream_t stream) {
    const float* x     = (const float*)d_in[0];
    const float* votes = (const float*)d_in[1];
    const int*   eidx  = (const int*)d_in[2];
    const int*   batch = (const int*)d_in[3];
    const float* W1l   = (const float*)d_in[4];
    const float* b1    = (const float*)d_in[5];
    const float* W1r   = (const float*)d_in[6];
    const float* W2l   = (const float*)d_in[7];
    const float* b2    = (const float*)d_in[8];
    const float* W2r   = (const float*)d_in[9];
    float* out = (float*)d_out;

    const int N = in_sizes[1];
    const int E = in_sizes[2] / 2;
    const int* src = eidx;
    const int* dst = eidx + E;
    const int nb = (N + CHUNK - 1) / CHUNK;
    const int E2 = E / 2;   // E is even (800000)

    char* ws = (char*)d_ws;
    size_t off = 0;
    int* deg_i      = (int*)(ws + off); off = align256(off + (size_t)N * 4);
    int* row_start  = (int*)(ws + off); off = align256(off + (size_t)(N + 1) * 4);
    int* cursor     = (int*)(ws + off); off = align256(off + (size_t)N * 4);
    int* bsum       = (int*)(ws + off); off = align256(off + (size_t)nb * 4);
    int* bsum_ex    = (int*)(ws + off); off = align256(off + (size_t)nb * 4);
    int* sorted_src = (int*)(ws + off); off = align256(off + (size_t)E * 4);
    ushort_t* xb    = (ushort_t*)(ws + off); off = align256(off + (size_t)N * IN_F * 2);
    ushort_t* agg1b = (ushort_t*)(ws + off); off = align256(off + (size_t)N * IN_F * 2);
    ushort_t* ub    = (ushort_t*)(ws + off); off = align256(off + (size_t)N * OUTD * 2);
    float* vv       = (float*)(ws + off); off = align256(off + (size_t)N * OUTD * 4);
    float* aggu     = (float*)(ws + off); off = align256(off + (size_t)N * OUTD * 4);
    ushort_t* bp1   = (ushort_t*)(ws + off); off = align256(off + (size_t)BP1_N * 2);
    ushort_t* bp2   = (ushort_t*)(ws + off); off = align256(off + (size_t)BP2_N * 2);

    hipMemsetAsync(deg_i, 0, (size_t)N * 4, stream);
    init_out_kernel<<<(out_size + 255) / 256, 256, 0, stream>>>(out, out_size);

    // CSR
    hist_kernel<<<(E2 + 255) / 256, 256, 0, stream>>>(dst, deg_i, E2);
    chunk_sum_kernel<<<nb, 256, 0, stream>>>(deg_i, bsum, N);
    scan_bsum_kernel<<<1, 64, 0, stream>>>(bsum, bsum_ex, nb);
    write_rows_kernel<<<nb, 256, 0, stream>>>(deg_i, bsum_ex, row_start, cursor, N, E);
    place_kernel<<<(E2 + 255) / 256, 256, 0, stream>>>(src, dst, cursor, sorted_src, E2);

    // conversions (xb; fragment-packed weights)
    convert_kernel<<<(N * IN_F + 255) / 256, 256, 0, stream>>>(x, votes, xb, N);
    convertw_kernel<<<(BP1_N + BP2_N + 255) / 256, 256, 0, stream>>>(W1l, W1r, W2l, W2r,
                                                                     bp1, bp2);

    // layer 1 aggregate + both dense matmuls via MFMA (h1 stays in LDS)
    gather1_kernel<<<(N + 3) / 4, 256, 0, stream>>>(xb, row_start, sorted_src, agg1b, N);
    gemm1_kernel<<<(N + T1_M - 1) / T1_M, 256, 0, stream>>>(xb, agg1b, bp1, bp2,
                                                            b1, ub, vv, N);
    // layer 2 aggregate (64 dims, bf16)
    gatheru_kernel<<<(N + 3) / 4, 256, 0, stream>>>(ub, row_start, sorted_src, aggu, N);

    // h2 = aggu + v + b2, fused with segment-max
    finalize_kernel<<<(N + SEG_NODES - 1) / SEG_NODES, 256, 0, stream>>>(
        aggu, vv, b2, batch, out, N);
}

// Round 12
// 161.704 us; speedup vs baseline: 1.9779x; 1.3017x over previous
//
#include <hip/hip_runtime.h>
#include <hip/hip_bf16.h>

#define IN_F 108   // concat(x[107], votes[1])
#define XD   107
#define HID  128
#define OUTD 64
#define SEG_NODES 64
#define BSH 6              // bucket = dst >> 6 (64 nodes per bucket)
#define BNODES 64
#define MAXBK 1024         // supports N <= 65536
#define EPB 4096           // edges per bscatter block
#define BP1_N (8 * 7 * 64 * 8)   // [ct][ks][lane][j] fragment-packed W1 (K=224 pad)
#define BP2_N (8 * 4 * 64 * 8)   // fragment-packed [W2l|W2r] (K=128)

typedef unsigned short ushort_t;
typedef unsigned int uint_t;
typedef __attribute__((ext_vector_type(8))) short bf16x8;
typedef __attribute__((ext_vector_type(4))) float f32x4;

__device__ inline void atomicMaxF(float* addr, float val) {
    if (val >= 0.f) atomicMax((int*)addr, __float_as_int(val));
    else            atomicMin((unsigned int*)addr, __float_as_uint(val));
}

__device__ inline ushort_t f2bf(float f) {
    uint_t b = __float_as_uint(f);
    return (ushort_t)((b + 0x7fffu + ((b >> 16) & 1u)) >> 16);   // RNE
}

__global__ void init_out_kernel(float* out, int n) {
    int i = blockIdx.x * 256 + threadIdx.x;
    if (i < n) out[i] = -__builtin_inff();
}

// ---- bucket sort stage A1: bucket histogram -----------------------------
__global__ __launch_bounds__(256) void bhist_kernel(const int* __restrict__ dst,
                                                    int* __restrict__ bcnt, int E, int nbk) {
    __shared__ int lh[MAXBK];
    for (int i = threadIdx.x; i < nbk; i += 256) lh[i] = 0;
    __syncthreads();
    int base = blockIdx.x * EPB;
    int end = min(base + EPB, E);
    for (int k = base + threadIdx.x; k < end; k += 256)
        atomicAdd(&lh[dst[k] >> BSH], 1);
    __syncthreads();
    for (int i = threadIdx.x; i < nbk; i += 256)
        if (lh[i] > 0) atomicAdd(&bcnt[i], lh[i]);
}

// ---- A2: exclusive scan of bucket counts (one wave) ---------------------
__global__ __launch_bounds__(64) void bscan_kernel(const int* __restrict__ bcnt,
                                                   int* __restrict__ bbase,
                                                   int* __restrict__ brsv,
                                                   int* __restrict__ row_start,
                                                   int nbk, int N, int E) {
    int lane = threadIdx.x;
    int carry = 0;
    for (int b = 0; b < nbk; b += 64) {
        int i = b + lane;
        int orig = (i < nbk) ? bcnt[i] : 0;
        int v = orig;
#pragma unroll
        for (int d = 1; d < 64; d <<= 1) {
            int t = __shfl_up(v, d);
            if (lane >= d) v += t;
        }
        if (i < nbk) {
            int ex = carry + v - orig;
            bbase[i] = ex;
            brsv[i] = ex;
        }
        carry += __shfl(v, 63);
    }
    if (lane == 0) {
        bbase[nbk] = E;
        row_start[N] = E;
    }
}

// ---- A3: scatter edges into bucket-grouped ebuf -------------------------
__global__ __launch_bounds__(256) void bscatter_kernel(const int* __restrict__ src,
                                                       const int* __restrict__ dst,
                                                       int* __restrict__ brsv,
                                                       int2* __restrict__ ebuf,
                                                       int E, int nbk) {
    __shared__ int lh[MAXBK];
    __shared__ int lofs[MAXBK];
    for (int i = threadIdx.x; i < nbk; i += 256) lh[i] = 0;
    __syncthreads();
    int base = blockIdx.x * EPB;
    int end = min(base + EPB, E);
    for (int k = base + threadIdx.x; k < end; k += 256)
        atomicAdd(&lh[dst[k] >> BSH], 1);
    __syncthreads();
    for (int i = threadIdx.x; i < nbk; i += 256)
        if (lh[i] > 0) lofs[i] = atomicAdd(&brsv[i], lh[i]);
    __syncthreads();
    for (int k = base + threadIdx.x; k < end; k += 256) {
        int d = dst[k];
        int pos = atomicAdd(&lofs[d >> BSH], 1);
        ebuf[pos] = make_int2(src[k], d);
    }
}

// ---- B: per-bucket CSR build (row_start + sorted_src) -------------------
__global__ __launch_bounds__(256) void bbuild_kernel(const int2* __restrict__ ebuf,
                                                     const int* __restrict__ bbase,
                                                     int* __restrict__ row_start,
                                                     int* __restrict__ sorted_src,
                                                     int N) {
    __shared__ int nh[BNODES];
    __shared__ int cur[BNODES];
    int b = blockIdx.x;
    int e0 = bbase[b], e1 = bbase[b + 1];
    int nlo = b << BSH;
    int nloc = min(BNODES, N - nlo);
    if (threadIdx.x < BNODES) nh[threadIdx.x] = 0;
    __syncthreads();
    for (int k = e0 + threadIdx.x; k < e1; k += 256)
        atomicAdd(&nh[ebuf[k].y & (BNODES - 1)], 1);
    __syncthreads();
    if (threadIdx.x < 64) {
        int lane = threadIdx.x;
        int orig = nh[lane];
        int v = orig;
#pragma unroll
        for (int d = 1; d < 64; d <<= 1) {
            int t = __shfl_up(v, d);
            if (lane >= d) v += t;
        }
        int ex = e0 + v - orig;
        cur[lane] = ex;
        if (lane < nloc) row_start[nlo + lane] = ex;
    }
    __syncthreads();
    for (int k = e0 + threadIdx.x; k < e1; k += 256) {
        int2 e = ebuf[k];
        int pos = atomicAdd(&cur[e.y & (BNODES - 1)], 1);
        sorted_src[pos] = e.x;
    }
}

// ---- bf16 copy of h0 ----------------------------------------------------
__global__ void convert_kernel(const float* __restrict__ x, const float* __restrict__ votes,
                               ushort_t* __restrict__ xb, int N) {
    int idx = blockIdx.x * 256 + threadIdx.x;
    if (idx >= N * IN_F) return;
    int n = idx / IN_F, f = idx - n * IN_F;
    float v = (f < XD) ? x[n * XD + f] : votes[n];
    xb[idx] = f2bf(v);
}

// ---- weights -> MFMA-fragment-packed bf16 (once per launch) -------------
__global__ void convertw_kernel(const float* __restrict__ W1l, const float* __restrict__ W1r,
                                const float* __restrict__ W2l, const float* __restrict__ W2r,
                                ushort_t* __restrict__ bp1, ushort_t* __restrict__ bp2) {
    int i = blockIdx.x * 256 + threadIdx.x;
    if (i < BP1_N) {
        int j = i & 7;
        int lane = (i >> 3) & 63;
        int rest = i >> 9;
        int ks = rest % 7;
        int ct = rest / 7;
        int k = ks * 32 + (lane >> 4) * 8 + j;
        int col = ct * 16 + (lane & 15);
        float v = 0.f;
        if (k < IN_F) v = W1l[k * HID + col];
        else if (k < 2 * IN_F) v = W1r[(k - IN_F) * HID + col];
        bp1[i] = f2bf(v);
    }
    int i2 = i - BP1_N;
    if (i2 >= 0 && i2 < BP2_N) {
        int j = i2 & 7;
        int lane = (i2 >> 3) & 63;
        int ks = (i2 >> 9) & 3;
        int ct = i2 >> 11;
        int k = ks * 32 + (lane >> 4) * 8 + j;
        int col = ct * 16 + (lane & 15);
        float v = (col < OUTD) ? W2l[k * OUTD + col] : W2r[k * OUTD + (col - OUTD)];
        bp2[i2] = f2bf(v);
    }
}

// ---- gather-mean layer 1 (bf16 in, f32 accum, bf16 out, pre-divided) ----
__global__ __launch_bounds__(256) void gather1_kernel(
        const ushort_t* __restrict__ xb,
        const int* __restrict__ row_start, const int* __restrict__ sorted_src,
        ushort_t* __restrict__ agg1b, int N) {
    int node = (blockIdx.x * 256 + threadIdx.x) >> 6;
    int lane = threadIdx.x & 63;
    if (node >= N) return;
    int rs = row_start[node], re = row_start[node + 1];
    int h  = lane >> 5;
    int l2 = lane & 31;
    float a0 = 0.f, a1 = 0.f, a2 = 0.f, a3 = 0.f;
    for (int k0 = rs; k0 < re; k0 += 64) {
        int cnt = min(64, re - k0);
        int sl = sorted_src[k0 + min(lane, cnt - 1)];
        for (int t = 0; t < cnt; t += 2) {
            int tt = min(t + h, cnt - 1);
            int s = __shfl(sl, tt);
            if (t + h < cnt && l2 < 27) {
                uint2 w = *(const uint2*)(xb + s * IN_F + 4 * l2);
                a0 += __uint_as_float(w.x << 16);
                a1 += __uint_as_float(w.x & 0xffff0000u);
                a2 += __uint_as_float(w.y << 16);
                a3 += __uint_as_float(w.y & 0xffff0000u);
            }
        }
    }
    a0 += __shfl_xor(a0, 32);
    a1 += __shfl_xor(a1, 32);
    a2 += __shfl_xor(a2, 32);
    a3 += __shfl_xor(a3, 32);
    float inv = 1.f / fmaxf((float)(re - rs), 1.f);
    if (lane < 27) {
        ushort4 p;
        p.x = f2bf(a0 * inv);
        p.y = f2bf(a1 * inv);
        p.z = f2bf(a2 * inv);
        p.w = f2bf(a3 * inv);
        *(ushort4*)(agg1b + node * IN_F + 4 * lane) = p;
    }
}

// ---- gather-mean of u (bf16, 64 dims) -----------------------------------
__global__ __launch_bounds__(256) void gatheru_kernel(
        const ushort_t* __restrict__ ub,
        const int* __restrict__ row_start, const int* __restrict__ sorted_src,
        float* __restrict__ aggu, int N) {
    int node = (blockIdx.x * 256 + threadIdx.x) >> 6;
    int lane = threadIdx.x & 63;
    if (node >= N) return;
    int rs = row_start[node], re = row_start[node + 1];
    int g  = lane >> 4;
    int l4 = lane & 15;
    float a0 = 0.f, a1 = 0.f, a2 = 0.f, a3 = 0.f;
    for (int k0 = rs; k0 < re; k0 += 64) {
        int cnt = min(64, re - k0);
        int sl = sorted_src[k0 + min(lane, cnt - 1)];
        for (int t = 0; t < cnt; t += 4) {
            int tt = min(t + g, cnt - 1);
            int s = __shfl(sl, tt);
            if (t + g < cnt) {
                uint2 w = *(const uint2*)(ub + (s << 6) + 4 * l4);
                a0 += __uint_as_float(w.x << 16);
                a1 += __uint_as_float(w.x & 0xffff0000u);
                a2 += __uint_as_float(w.y << 16);
                a3 += __uint_as_float(w.y & 0xffff0000u);
            }
        }
    }
    a0 += __shfl_xor(a0, 16); a0 += __shfl_xor(a0, 32);
    a1 += __shfl_xor(a1, 16); a1 += __shfl_xor(a1, 32);
    a2 += __shfl_xor(a2, 16); a2 += __shfl_xor(a2, 32);
    a3 += __shfl_xor(a3, 16); a3 += __shfl_xor(a3, 32);
    float inv = 1.f / fmaxf((float)(re - rs), 1.f);
    if (lane < 16) {
        *(float4*)(aggu + (node << 6) + 4 * lane) =
            make_float4(a0 * inv, a1 * inv, a2 * inv, a3 * inv);
    }
}

// ---- MFMA fused dense ----------------------------------------------------
#define T1_M 32
#define A_STRIDE_US 232
#define A_STRIDE_U  116
#define H1_STRIDE_US 136
__global__ __launch_bounds__(256) void gemm1_kernel(
        const ushort_t* __restrict__ xb, const ushort_t* __restrict__ agg1b,
        const ushort_t* __restrict__ bp1, const ushort_t* __restrict__ bp2,
        const float* __restrict__ b1,
        ushort_t* __restrict__ ub, float* __restrict__ vv, int N) {
    __shared__ uint_t smem[T1_M * A_STRIDE_U];      // 14848 B
    int n0 = blockIdx.x * T1_M;
    for (int i = threadIdx.x; i < T1_M * 112; i += 256) {
        int m = i / 112, c = i - m * 112;
        int n = n0 + m;
        uint_t v = 0u;
        if (n < N) {
            if (c < 54)       v = ((const uint_t*)(agg1b + n * IN_F))[c];
            else if (c < 108) v = ((const uint_t*)(xb + n * IN_F))[c - 54];
        }
        smem[m * A_STRIDE_U + c] = v;
    }
    __syncthreads();

    int lane = threadIdx.x & 63;
    int wid  = threadIdx.x >> 6;
    int wrow = (wid & 1) << 4;
    int wcol = (wid >> 1) << 6;
    int arow = wrow + (lane & 15);
    int akoff = (lane >> 4) * 8;
    const ushort_t* sA = (const ushort_t*)smem;
    const bf16x8* bp1v = (const bf16x8*)bp1;

    f32x4 acc0 = {}, acc1 = {}, acc2_ = {}, acc3 = {};
    int ct0 = wcol >> 4;
#pragma unroll
    for (int ks = 0; ks < 7; ++ks) {
        bf16x8 af = *(const bf16x8*)(sA + arow * A_STRIDE_US + ks * 32 + akoff);
        bf16x8 bf0 = bp1v[((ct0 + 0) * 7 + ks) * 64 + lane];
        bf16x8 bf1 = bp1v[((ct0 + 1) * 7 + ks) * 64 + lane];
        bf16x8 bf2 = bp1v[((ct0 + 2) * 7 + ks) * 64 + lane];
        bf16x8 bf3 = bp1v[((ct0 + 3) * 7 + ks) * 64 + lane];
        acc0 = __builtin_amdgcn_mfma_f32_16x16x32_bf16(af, bf0, acc0, 0, 0, 0);
        acc1 = __builtin_amdgcn_mfma_f32_16x16x32_bf16(af, bf1, acc1, 0, 0, 0);
        acc2_ = __builtin_amdgcn_mfma_f32_16x16x32_bf16(af, bf2, acc2_, 0, 0, 0);
        acc3 = __builtin_amdgcn_mfma_f32_16x16x32_bf16(af, bf3, acc3, 0, 0, 0);
    }

    __syncthreads();
    ushort_t* sh1 = (ushort_t*)smem;
    {
        int colb = wcol + (lane & 15);
        int rowb = wrow + ((lane >> 4) << 2);
#pragma unroll
        for (int t = 0; t < 4; ++t) {
            f32x4 a = (t == 0) ? acc0 : (t == 1) ? acc1 : (t == 2) ? acc2_ : acc3;
            int col = colb + t * 16;
            float bj = b1[col];
#pragma unroll
            for (int r = 0; r < 4; ++r)
                sh1[(rowb + r) * H1_STRIDE_US + col] = f2bf(fmaxf(a[r] + bj, 0.f));
        }
    }
    __syncthreads();

    const bf16x8* bp2v = (const bf16x8*)bp2;
    f32x4 dcc0 = {}, dcc1 = {}, dcc2 = {}, dcc3 = {};
#pragma unroll
    for (int ks = 0; ks < 4; ++ks) {
        bf16x8 af = *(const bf16x8*)(sh1 + arow * H1_STRIDE_US + ks * 32 + akoff);
        bf16x8 bf0 = bp2v[((ct0 + 0) * 4 + ks) * 64 + lane];
        bf16x8 bf1 = bp2v[((ct0 + 1) * 4 + ks) * 64 + lane];
        bf16x8 bf2 = bp2v[((ct0 + 2) * 4 + ks) * 64 + lane];
        bf16x8 bf3 = bp2v[((ct0 + 3) * 4 + ks) * 64 + lane];
        dcc0 = __builtin_amdgcn_mfma_f32_16x16x32_bf16(af, bf0, dcc0, 0, 0, 0);
        dcc1 = __builtin_amdgcn_mfma_f32_16x16x32_bf16(af, bf1, dcc1, 0, 0, 0);
        dcc2 = __builtin_amdgcn_mfma_f32_16x16x32_bf16(af, bf2, dcc2, 0, 0, 0);
        dcc3 = __builtin_amdgcn_mfma_f32_16x16x32_bf16(af, bf3, dcc3, 0, 0, 0);
    }

    {
        int colb = wcol + (lane & 15);
        int rowb = wrow + ((lane >> 4) << 2);
#pragma unroll
        for (int t = 0; t < 4; ++t) {
            f32x4 a = (t == 0) ? dcc0 : (t == 1) ? dcc1 : (t == 2) ? dcc2 : dcc3;
            int col = colb + t * 16;
#pragma unroll
            for (int r = 0; r < 4; ++r) {
                int n = n0 + rowb + r;
                if (n < N) {
                    if (col < OUTD) ub[(n << 6) + col] = f2bf(a[r]);
                    else            vv[(n << 6) + (col - OUTD)] = a[r];
                }
            }
        }
    }
}

// ---- finalize: h2 = aggu + v + b2, then run-length segment-max ----------
__global__ __launch_bounds__(256) void finalize_kernel(
        const float* __restrict__ aggu, const float* __restrict__ vv,
        const float* __restrict__ b2, const int* __restrict__ batch,
        float* __restrict__ out, int N) {
    int j  = threadIdx.x & 63;
    int nq = threadIdx.x >> 6;
    int n0 = blockIdx.x * SEG_NODES;
    float bj = b2[j];
    int curg = -1;
    float curm = -__builtin_inff();
    for (int m = nq; m < SEG_NODES; m += 4) {
        int n = n0 + m;
        if (n >= N) break;
        int g = batch[n];
        float v = aggu[(n << 6) + j] + vv[(n << 6) + j] + bj;
        if (g != curg) {
            if (curg >= 0) atomicMaxF(&out[(curg << 6) + j], curm);
            curg = g;
            curm = v;
        } else {
            curm = fmaxf(curm, v);
        }
    }
    if (curg >= 0) atomicMaxF(&out[(curg << 6) + j], curm);
}

static inline size_t align256(size_t v) { return (v + 255) & ~(size_t)255; }

extern "C" void kernel_launch(void* const* d_in, const int* in_sizes, int n_in,
                              void* d_out, int out_size, void* d_ws, size_t ws_size,
                              hipStream_t stream) {
    const float* x     = (const float*)d_in[0];
    const float* votes = (const float*)d_in[1];
    const int*   eidx  = (const int*)d_in[2];
    const int*   batch = (const int*)d_in[3];
    const float* W1l   = (const float*)d_in[4];
    const float* b1    = (const float*)d_in[5];
    const float* W1r   = (const float*)d_in[6];
    const float* W2l   = (const float*)d_in[7];
    const float* b2    = (const float*)d_in[8];
    const float* W2r   = (const float*)d_in[9];
    float* out = (float*)d_out;

    const int N = in_sizes[1];
    const int E = in_sizes[2] / 2;
    const int* src = eidx;
    const int* dst = eidx + E;
    const int nbk = (N + BNODES - 1) >> BSH;   // 782 for N=50000

    char* ws = (char*)d_ws;
    size_t off = 0;
    int* bcnt       = (int*)(ws + off); off = align256(off + (size_t)nbk * 4);
    int* bbase      = (int*)(ws + off); off = align256(off + (size_t)(nbk + 1) * 4);
    int* brsv       = (int*)(ws + off); off = align256(off + (size_t)nbk * 4);
    int* row_start  = (int*)(ws + off); off = align256(off + (size_t)(N + 1) * 4);
    int2* ebuf      = (int2*)(ws + off); off = align256(off + (size_t)E * 8);
    int* sorted_src = (int*)(ws + off); off = align256(off + (size_t)E * 4);
    ushort_t* xb    = (ushort_t*)(ws + off); off = align256(off + (size_t)N * IN_F * 2);
    ushort_t* agg1b = (ushort_t*)(ws + off); off = align256(off + (size_t)N * IN_F * 2);
    ushort_t* ub    = (ushort_t*)(ws + off); off = align256(off + (size_t)N * OUTD * 2);
    float* vv       = (float*)(ws + off); off = align256(off + (size_t)N * OUTD * 4);
    float* aggu     = (float*)(ws + off); off = align256(off + (size_t)N * OUTD * 4);
    ushort_t* bp1   = (ushort_t*)(ws + off); off = align256(off + (size_t)BP1_N * 2);
    ushort_t* bp2   = (ushort_t*)(ws + off); off = align256(off + (size_t)BP2_N * 2);

    hipMemsetAsync(bcnt, 0, (size_t)nbk * 4, stream);
    init_out_kernel<<<(out_size + 255) / 256, 256, 0, stream>>>(out, out_size);

    // bucket counting sort -> CSR
    int nebl = (E + EPB - 1) / EPB;
    bhist_kernel<<<nebl, 256, 0, stream>>>(dst, bcnt, E, nbk);
    bscan_kernel<<<1, 64, 0, stream>>>(bcnt, bbase, brsv, row_start, nbk, N, E);
    bscatter_kernel<<<nebl, 256, 0, stream>>>(src, dst, brsv, ebuf, E, nbk);
    bbuild_kernel<<<nbk, 256, 0, stream>>>(ebuf, bbase, row_start, sorted_src, N);

    // conversions (xb; fragment-packed weights)
    convert_kernel<<<(N * IN_F + 255) / 256, 256, 0, stream>>>(x, votes, xb, N);
    convertw_kernel<<<(BP1_N + BP2_N + 255) / 256, 256, 0, stream>>>(W1l, W1r, W2l, W2r,
                                                                     bp1, bp2);

    // layer 1 aggregate + both dense matmuls via MFMA (h1 stays in LDS)
    gather1_kernel<<<(N + 3) / 4, 256, 0, stream>>>(xb, row_start, sorted_src, agg1b, N);
    gemm1_kernel<<<(N + T1_M - 1) / T1_M, 256, 0, stream>>>(xb, agg1b, bp1, bp2,
                                                            b1, ub, vv, N);
    // layer 2 aggregate (64 dims, bf16)
    gatheru_kernel<<<(N + 3) / 4, 256, 0, stream>>>(ub, row_start, sorted_src, aggu, N);

    // h2 = aggu + v + b2, fused with segment-max
    finalize_kernel<<<(N + SEG_NODES - 1) / SEG_NODES, 256, 0, stream>>>(
        aggu, vv, b2, batch, out, N);
}

// Round 13
// 147.983 us; speedup vs baseline: 2.1613x; 1.0927x over previous
//
#include <hip/hip_runtime.h>
#include <hip/hip_bf16.h>

#define IN_F 108   // concat(x[107], votes[1])
#define XD   107
#define HID  128
#define OUTD 64
#define SEG_NODES 64
#define BSH 6              // bucket = dst >> 6 (64 nodes per bucket)
#define BNODES 64
#define MAXBK 1024         // supports N <= 65536
#define EPB 4096           // edges per bscatter block
#define SRCMASK 0x03FFFFFF
#define BP1_N (8 * 7 * 64 * 8)   // [ct][ks][lane][j] fragment-packed W1 (K=224 pad)
#define BP2_N (8 * 4 * 64 * 8)   // fragment-packed [W2l|W2r] (K=128)

typedef unsigned short ushort_t;
typedef unsigned int uint_t;
typedef __attribute__((ext_vector_type(8))) short bf16x8;
typedef __attribute__((ext_vector_type(4))) float f32x4;

__device__ inline void atomicMaxF(float* addr, float val) {
    if (val >= 0.f) atomicMax((int*)addr, __float_as_int(val));
    else            atomicMin((unsigned int*)addr, __float_as_uint(val));
}

__device__ inline ushort_t f2bf(float f) {
    uint_t b = __float_as_uint(f);
    return (ushort_t)((b + 0x7fffu + ((b >> 16) & 1u)) >> 16);   // RNE
}

__global__ void init_out_kernel(float* out, int n) {
    int i = blockIdx.x * 256 + threadIdx.x;
    if (i < n) out[i] = -__builtin_inff();
}

__global__ void zero_kernel(int* p, int n) {
    int i = blockIdx.x * 256 + threadIdx.x;
    if (i < n) p[i] = 0;
}

// ---- bucket sort stage A1: bucket histogram -----------------------------
__global__ __launch_bounds__(256) void bhist_kernel(const int* __restrict__ dst,
                                                    int* __restrict__ bcnt, int E, int nbk) {
    __shared__ int lh[MAXBK];
    for (int i = threadIdx.x; i < nbk; i += 256) lh[i] = 0;
    __syncthreads();
    int base = blockIdx.x * EPB;
    int end = min(base + EPB, E);
    for (int k = base + threadIdx.x; k < end; k += 256)
        atomicAdd(&lh[dst[k] >> BSH], 1);
    __syncthreads();
    for (int i = threadIdx.x; i < nbk; i += 256)
        if (lh[i] > 0) atomicAdd(&bcnt[i], lh[i]);
}

// ---- A2: exclusive scan of bucket counts (one wave) ---------------------
__global__ __launch_bounds__(64) void bscan_kernel(const int* __restrict__ bcnt,
                                                   int* __restrict__ bbase,
                                                   int* __restrict__ brsv,
                                                   int* __restrict__ row_start,
                                                   int nbk, int N, int E) {
    int lane = threadIdx.x;
    int carry = 0;
    for (int b = 0; b < nbk; b += 64) {
        int i = b + lane;
        int orig = (i < nbk) ? bcnt[i] : 0;
        int v = orig;
#pragma unroll
        for (int d = 1; d < 64; d <<= 1) {
            int t = __shfl_up(v, d);
            if (lane >= d) v += t;
        }
        if (i < nbk) {
            int ex = carry + v - orig;
            bbase[i] = ex;
            brsv[i] = ex;
        }
        carry += __shfl(v, 63);
    }
    if (lane == 0) {
        bbase[nbk] = E;
        row_start[N] = E;
    }
}

// ---- A3: scatter edges into bucket-grouped ebuf (packed uint) -----------
__global__ __launch_bounds__(256) void bscatter_kernel(const int* __restrict__ src,
                                                       const int* __restrict__ dst,
                                                       int* __restrict__ brsv,
                                                       uint_t* __restrict__ ebuf,
                                                       int E, int nbk) {
    __shared__ int lh[MAXBK];
    __shared__ int lofs[MAXBK];
    for (int i = threadIdx.x; i < nbk; i += 256) lh[i] = 0;
    __syncthreads();
    int base = blockIdx.x * EPB;
    int end = min(base + EPB, E);
    for (int k = base + threadIdx.x; k < end; k += 256)
        atomicAdd(&lh[dst[k] >> BSH], 1);
    __syncthreads();
    for (int i = threadIdx.x; i < nbk; i += 256)
        if (lh[i] > 0) lofs[i] = atomicAdd(&brsv[i], lh[i]);
    __syncthreads();
    for (int k = base + threadIdx.x; k < end; k += 256) {
        int d = dst[k];
        int pos = atomicAdd(&lofs[d >> BSH], 1);
        ebuf[pos] = (uint_t)src[k] | ((uint_t)(d & (BNODES - 1)) << 26);
    }
}

// ---- B: per-bucket CSR build (row_start + sorted_src) -------------------
__global__ __launch_bounds__(256) void bbuild_kernel(const uint_t* __restrict__ ebuf,
                                                     const int* __restrict__ bbase,
                                                     int* __restrict__ row_start,
                                                     int* __restrict__ sorted_src,
                                                     int N) {
    __shared__ int nh[BNODES];
    __shared__ int cur[BNODES];
    int b = blockIdx.x;
    int e0 = bbase[b], e1 = bbase[b + 1];
    int nlo = b << BSH;
    int nloc = min(BNODES, N - nlo);
    if (threadIdx.x < BNODES) nh[threadIdx.x] = 0;
    __syncthreads();
    for (int k = e0 + threadIdx.x; k < e1; k += 256)
        atomicAdd(&nh[ebuf[k] >> 26], 1);
    __syncthreads();
    if (threadIdx.x < 64) {
        int lane = threadIdx.x;
        int orig = nh[lane];
        int v = orig;
#pragma unroll
        for (int d = 1; d < 64; d <<= 1) {
            int t = __shfl_up(v, d);
            if (lane >= d) v += t;
        }
        int ex = e0 + v - orig;
        cur[lane] = ex;
        if (lane < nloc) row_start[nlo + lane] = ex;
    }
    __syncthreads();
    for (int k = e0 + threadIdx.x; k < e1; k += 256) {
        uint_t e = ebuf[k];
        int pos = atomicAdd(&cur[e >> 26], 1);
        sorted_src[pos] = (int)(e & SRCMASK);
    }
}

// ---- bf16 copy of h0 ----------------------------------------------------
__global__ void convert_kernel(const float* __restrict__ x, const float* __restrict__ votes,
                               ushort_t* __restrict__ xb, int N) {
    int idx = blockIdx.x * 256 + threadIdx.x;
    if (idx >= N * IN_F) return;
    int n = idx / IN_F, f = idx - n * IN_F;
    float v = (f < XD) ? x[n * XD + f] : votes[n];
    xb[idx] = f2bf(v);
}

// ---- weights -> MFMA-fragment-packed bf16 (once per launch) -------------
__global__ void convertw_kernel(const float* __restrict__ W1l, const float* __restrict__ W1r,
                                const float* __restrict__ W2l, const float* __restrict__ W2r,
                                ushort_t* __restrict__ bp1, ushort_t* __restrict__ bp2) {
    int i = blockIdx.x * 256 + threadIdx.x;
    if (i < BP1_N) {
        int j = i & 7;
        int lane = (i >> 3) & 63;
        int rest = i >> 9;
        int ks = rest % 7;
        int ct = rest / 7;
        int k = ks * 32 + (lane >> 4) * 8 + j;
        int col = ct * 16 + (lane & 15);
        float v = 0.f;
        if (k < IN_F) v = W1l[k * HID + col];
        else if (k < 2 * IN_F) v = W1r[(k - IN_F) * HID + col];
        bp1[i] = f2bf(v);
    }
    int i2 = i - BP1_N;
    if (i2 >= 0 && i2 < BP2_N) {
        int j = i2 & 7;
        int lane = (i2 >> 3) & 63;
        int ks = (i2 >> 9) & 3;
        int ct = i2 >> 11;
        int k = ks * 32 + (lane >> 4) * 8 + j;
        int col = ct * 16 + (lane & 15);
        float v = (col < OUTD) ? W2l[k * OUTD + col] : W2r[k * OUTD + (col - OUTD)];
        bp2[i2] = f2bf(v);
    }
}

// ---- gather-mean layer 1 (unroll x4 for MLP) ----------------------------
__global__ __launch_bounds__(256) void gather1_kernel(
        const ushort_t* __restrict__ xb,
        const int* __restrict__ row_start, const int* __restrict__ sorted_src,
        ushort_t* __restrict__ agg1b, int N) {
    int node = (blockIdx.x * 256 + threadIdx.x) >> 6;
    int lane = threadIdx.x & 63;
    if (node >= N) return;
    int rs = row_start[node], re = row_start[node + 1];
    int h  = lane >> 5;
    int l2 = lane & 31;
    float a0 = 0.f, a1 = 0.f, a2 = 0.f, a3 = 0.f;
    for (int k0 = rs; k0 < re; k0 += 64) {
        int cnt = min(64, re - k0);
        int sl = sorted_src[k0 + min(lane, cnt - 1)];
        int t = 0;
        for (; t + 8 <= cnt; t += 8) {
            int s0 = __shfl(sl, t + h);
            int s1 = __shfl(sl, t + 2 + h);
            int s2 = __shfl(sl, t + 4 + h);
            int s3 = __shfl(sl, t + 6 + h);
            if (l2 < 27) {
                uint2 w0 = *(const uint2*)(xb + s0 * IN_F + 4 * l2);
                uint2 w1 = *(const uint2*)(xb + s1 * IN_F + 4 * l2);
                uint2 w2 = *(const uint2*)(xb + s2 * IN_F + 4 * l2);
                uint2 w3 = *(const uint2*)(xb + s3 * IN_F + 4 * l2);
                a0 += __uint_as_float(w0.x << 16) + __uint_as_float(w1.x << 16)
                    + __uint_as_float(w2.x << 16) + __uint_as_float(w3.x << 16);
                a1 += __uint_as_float(w0.x & 0xffff0000u) + __uint_as_float(w1.x & 0xffff0000u)
                    + __uint_as_float(w2.x & 0xffff0000u) + __uint_as_float(w3.x & 0xffff0000u);
                a2 += __uint_as_float(w0.y << 16) + __uint_as_float(w1.y << 16)
                    + __uint_as_float(w2.y << 16) + __uint_as_float(w3.y << 16);
                a3 += __uint_as_float(w0.y & 0xffff0000u) + __uint_as_float(w1.y & 0xffff0000u)
                    + __uint_as_float(w2.y & 0xffff0000u) + __uint_as_float(w3.y & 0xffff0000u);
            }
        }
        for (; t < cnt; t += 2) {
            int tt = min(t + h, cnt - 1);
            int s = __shfl(sl, tt);
            if (t + h < cnt && l2 < 27) {
                uint2 w = *(const uint2*)(xb + s * IN_F + 4 * l2);
                a0 += __uint_as_float(w.x << 16);
                a1 += __uint_as_float(w.x & 0xffff0000u);
                a2 += __uint_as_float(w.y << 16);
                a3 += __uint_as_float(w.y & 0xffff0000u);
            }
        }
    }
    a0 += __shfl_xor(a0, 32);
    a1 += __shfl_xor(a1, 32);
    a2 += __shfl_xor(a2, 32);
    a3 += __shfl_xor(a3, 32);
    float inv = 1.f / fmaxf((float)(re - rs), 1.f);
    if (lane < 27) {
        ushort4 p;
        p.x = f2bf(a0 * inv);
        p.y = f2bf(a1 * inv);
        p.z = f2bf(a2 * inv);
        p.w = f2bf(a3 * inv);
        *(ushort4*)(agg1b + node * IN_F + 4 * lane) = p;
    }
}

// ---- gather-mean of u (bf16, 64 dims; unroll x2 -> 8 neighbors/iter) ----
__global__ __launch_bounds__(256) void gatheru_kernel(
        const ushort_t* __restrict__ ub,
        const int* __restrict__ row_start, const int* __restrict__ sorted_src,
        float* __restrict__ aggu, int N) {
    int node = (blockIdx.x * 256 + threadIdx.x) >> 6;
    int lane = threadIdx.x & 63;
    if (node >= N) return;
    int rs = row_start[node], re = row_start[node + 1];
    int g  = lane >> 4;
    int l4 = lane & 15;
    float a0 = 0.f, a1 = 0.f, a2 = 0.f, a3 = 0.f;
    for (int k0 = rs; k0 < re; k0 += 64) {
        int cnt = min(64, re - k0);
        int sl = sorted_src[k0 + min(lane, cnt - 1)];
        int t = 0;
        for (; t + 8 <= cnt; t += 8) {
            int s0 = __shfl(sl, t + g);
            int s1 = __shfl(sl, t + 4 + g);
            uint2 w0 = *(const uint2*)(ub + (s0 << 6) + 4 * l4);
            uint2 w1 = *(const uint2*)(ub + (s1 << 6) + 4 * l4);
            a0 += __uint_as_float(w0.x << 16) + __uint_as_float(w1.x << 16);
            a1 += __uint_as_float(w0.x & 0xffff0000u) + __uint_as_float(w1.x & 0xffff0000u);
            a2 += __uint_as_float(w0.y << 16) + __uint_as_float(w1.y << 16);
            a3 += __uint_as_float(w0.y & 0xffff0000u) + __uint_as_float(w1.y & 0xffff0000u);
        }
        for (; t < cnt; t += 4) {
            int tt = min(t + g, cnt - 1);
            int s = __shfl(sl, tt);
            if (t + g < cnt) {
                uint2 w = *(const uint2*)(ub + (s << 6) + 4 * l4);
                a0 += __uint_as_float(w.x << 16);
                a1 += __uint_as_float(w.x & 0xffff0000u);
                a2 += __uint_as_float(w.y << 16);
                a3 += __uint_as_float(w.y & 0xffff0000u);
            }
        }
    }
    a0 += __shfl_xor(a0, 16); a0 += __shfl_xor(a0, 32);
    a1 += __shfl_xor(a1, 16); a1 += __shfl_xor(a1, 32);
    a2 += __shfl_xor(a2, 16); a2 += __shfl_xor(a2, 32);
    a3 += __shfl_xor(a3, 16); a3 += __shfl_xor(a3, 32);
    float inv = 1.f / fmaxf((float)(re - rs), 1.f);
    if (lane < 16) {
        *(float4*)(aggu + (node << 6) + 4 * lane) =
            make_float4(a0 * inv, a1 * inv, a2 * inv, a3 * inv);
    }
}

// ---- MFMA fused dense ----------------------------------------------------
#define T1_M 32
#define A_STRIDE_US 232
#define A_STRIDE_U  116
#define H1_STRIDE_US 136
__global__ __launch_bounds__(256) void gemm1_kernel(
        const ushort_t* __restrict__ xb, const ushort_t* __restrict__ agg1b,
        const ushort_t* __restrict__ bp1, const ushort_t* __restrict__ bp2,
        const float* __restrict__ b1,
        ushort_t* __restrict__ ub, float* __restrict__ vv, int N) {
    __shared__ uint_t smem[T1_M * A_STRIDE_U];      // 14848 B
    int n0 = blockIdx.x * T1_M;
    for (int i = threadIdx.x; i < T1_M * 112; i += 256) {
        int m = i / 112, c = i - m * 112;
        int n = n0 + m;
        uint_t v = 0u;
        if (n < N) {
            if (c < 54)       v = ((const uint_t*)(agg1b + n * IN_F))[c];
            else if (c < 108) v = ((const uint_t*)(xb + n * IN_F))[c - 54];
        }
        smem[m * A_STRIDE_U + c] = v;
    }
    __syncthreads();

    int lane = threadIdx.x & 63;
    int wid  = threadIdx.x >> 6;
    int wrow = (wid & 1) << 4;
    int wcol = (wid >> 1) << 6;
    int arow = wrow + (lane & 15);
    int akoff = (lane >> 4) * 8;
    const ushort_t* sA = (const ushort_t*)smem;
    const bf16x8* bp1v = (const bf16x8*)bp1;

    f32x4 acc0 = {}, acc1 = {}, acc2_ = {}, acc3 = {};
    int ct0 = wcol >> 4;
#pragma unroll
    for (int ks = 0; ks < 7; ++ks) {
        bf16x8 af = *(const bf16x8*)(sA + arow * A_STRIDE_US + ks * 32 + akoff);
        bf16x8 bf0 = bp1v[((ct0 + 0) * 7 + ks) * 64 + lane];
        bf16x8 bf1 = bp1v[((ct0 + 1) * 7 + ks) * 64 + lane];
        bf16x8 bf2 = bp1v[((ct0 + 2) * 7 + ks) * 64 + lane];
        bf16x8 bf3 = bp1v[((ct0 + 3) * 7 + ks) * 64 + lane];
        acc0 = __builtin_amdgcn_mfma_f32_16x16x32_bf16(af, bf0, acc0, 0, 0, 0);
        acc1 = __builtin_amdgcn_mfma_f32_16x16x32_bf16(af, bf1, acc1, 0, 0, 0);
        acc2_ = __builtin_amdgcn_mfma_f32_16x16x32_bf16(af, bf2, acc2_, 0, 0, 0);
        acc3 = __builtin_amdgcn_mfma_f32_16x16x32_bf16(af, bf3, acc3, 0, 0, 0);
    }

    __syncthreads();
    ushort_t* sh1 = (ushort_t*)smem;
    {
        int colb = wcol + (lane & 15);
        int rowb = wrow + ((lane >> 4) << 2);
#pragma unroll
        for (int t = 0; t < 4; ++t) {
            f32x4 a = (t == 0) ? acc0 : (t == 1) ? acc1 : (t == 2) ? acc2_ : acc3;
            int col = colb + t * 16;
            float bj = b1[col];
#pragma unroll
            for (int r = 0; r < 4; ++r)
                sh1[(rowb + r) * H1_STRIDE_US + col] = f2bf(fmaxf(a[r] + bj, 0.f));
        }
    }
    __syncthreads();

    const bf16x8* bp2v = (const bf16x8*)bp2;
    f32x4 dcc0 = {}, dcc1 = {}, dcc2 = {}, dcc3 = {};
#pragma unroll
    for (int ks = 0; ks < 4; ++ks) {
        bf16x8 af = *(const bf16x8*)(sh1 + arow * H1_STRIDE_US + ks * 32 + akoff);
        bf16x8 bf0 = bp2v[((ct0 + 0) * 4 + ks) * 64 + lane];
        bf16x8 bf1 = bp2v[((ct0 + 1) * 4 + ks) * 64 + lane];
        bf16x8 bf2 = bp2v[((ct0 + 2) * 4 + ks) * 64 + lane];
        bf16x8 bf3 = bp2v[((ct0 + 3) * 4 + ks) * 64 + lane];
        dcc0 = __builtin_amdgcn_mfma_f32_16x16x32_bf16(af, bf0, dcc0, 0, 0, 0);
        dcc1 = __builtin_amdgcn_mfma_f32_16x16x32_bf16(af, bf1, dcc1, 0, 0, 0);
        dcc2 = __builtin_amdgcn_mfma_f32_16x16x32_bf16(af, bf2, dcc2, 0, 0, 0);
        dcc3 = __builtin_amdgcn_mfma_f32_16x16x32_bf16(af, bf3, dcc3, 0, 0, 0);
    }

    {
        int colb = wcol + (lane & 15);
        int rowb = wrow + ((lane >> 4) << 2);
#pragma unroll
        for (int t = 0; t < 4; ++t) {
            f32x4 a = (t == 0) ? dcc0 : (t == 1) ? dcc1 : (t == 2) ? dcc2 : dcc3;
            int col = colb + t * 16;
#pragma unroll
            for (int r = 0; r < 4; ++r) {
                int n = n0 + rowb + r;
                if (n < N) {
                    if (col < OUTD) ub[(n << 6) + col] = f2bf(a[r]);
                    else            vv[(n << 6) + (col - OUTD)] = a[r];
                }
            }
        }
    }
}

// ---- finalize: h2 = aggu + v + b2, then run-length segment-max ----------
__global__ __launch_bounds__(256) void finalize_kernel(
        const float* __restrict__ aggu, const float* __restrict__ vv,
        const float* __restrict__ b2, const int* __restrict__ batch,
        float* __restrict__ out, int N) {
    int j  = threadIdx.x & 63;
    int nq = threadIdx.x >> 6;
    int n0 = blockIdx.x * SEG_NODES;
    float bj = b2[j];
    int curg = -1;
    float curm = -__builtin_inff();
    for (int m = nq; m < SEG_NODES; m += 4) {
        int n = n0 + m;
        if (n >= N) break;
        int g = batch[n];
        float v = aggu[(n << 6) + j] + vv[(n << 6) + j] + bj;
        if (g != curg) {
            if (curg >= 0) atomicMaxF(&out[(curg << 6) + j], curm);
            curg = g;
            curm = v;
        } else {
            curm = fmaxf(curm, v);
        }
    }
    if (curg >= 0) atomicMaxF(&out[(curg << 6) + j], curm);
}

static inline size_t align256(size_t v) { return (v + 255) & ~(size_t)255; }

extern "C" void kernel_launch(void* const* d_in, const int* in_sizes, int n_in,
                              void* d_out, int out_size, void* d_ws, size_t ws_size,
                              hipStream_t stream) {
    const float* x     = (const float*)d_in[0];
    const float* votes = (const float*)d_in[1];
    const int*   eidx  = (const int*)d_in[2];
    const int*   batch = (const int*)d_in[3];
    const float* W1l   = (const float*)d_in[4];
    const float* b1    = (const float*)d_in[5];
    const float* W1r   = (const float*)d_in[6];
    const float* W2l   = (const float*)d_in[7];
    const float* b2    = (const float*)d_in[8];
    const float* W2r   = (const float*)d_in[9];
    float* out = (float*)d_out;

    const int N = in_sizes[1];
    const int E = in_sizes[2] / 2;
    const int* src = eidx;
    const int* dst = eidx + E;
    const int nbk = (N + BNODES - 1) >> BSH;   // 782 for N=50000

    char* ws = (char*)d_ws;
    size_t off = 0;
    int* bcnt       = (int*)(ws + off); off = align256(off + (size_t)nbk * 4);
    int* bbase      = (int*)(ws + off); off = align256(off + (size_t)(nbk + 1) * 4);
    int* brsv       = (int*)(ws + off); off = align256(off + (size_t)nbk * 4);
    int* row_start  = (int*)(ws + off); off = align256(off + (size_t)(N + 1) * 4);
    uint_t* ebuf    = (uint_t*)(ws + off); off = align256(off + (size_t)E * 4);
    int* sorted_src = (int*)(ws + off); off = align256(off + (size_t)E * 4);
    ushort_t* xb    = (ushort_t*)(ws + off); off = align256(off + (size_t)N * IN_F * 2);
    ushort_t* agg1b = (ushort_t*)(ws + off); off = align256(off + (size_t)N * IN_F * 2);
    ushort_t* ub    = (ushort_t*)(ws + off); off = align256(off + (size_t)N * OUTD * 2);
    float* vv       = (float*)(ws + off); off = align256(off + (size_t)N * OUTD * 4);
    float* aggu     = (float*)(ws + off); off = align256(off + (size_t)N * OUTD * 4);
    ushort_t* bp1   = (ushort_t*)(ws + off); off = align256(off + (size_t)BP1_N * 2);
    ushort_t* bp2   = (ushort_t*)(ws + off); off = align256(off + (size_t)BP2_N * 2);

    zero_kernel<<<(nbk + 255) / 256, 256, 0, stream>>>(bcnt, nbk);
    init_out_kernel<<<(out_size + 255) / 256, 256, 0, stream>>>(out, out_size);

    // bucket counting sort -> CSR
    int nebl = (E + EPB - 1) / EPB;
    bhist_kernel<<<nebl, 256, 0, stream>>>(dst, bcnt, E, nbk);
    bscan_kernel<<<1, 64, 0, stream>>>(bcnt, bbase, brsv, row_start, nbk, N, E);
    bscatter_kernel<<<nebl, 256, 0, stream>>>(src, dst, brsv, ebuf, E, nbk);
    bbuild_kernel<<<nbk, 256, 0, stream>>>(ebuf, bbase, row_start, sorted_src, N);

    // conversions (xb; fragment-packed weights)
    convert_kernel<<<(N * IN_F + 255) / 256, 256, 0, stream>>>(x, votes, xb, N);
    convertw_kernel<<<(BP1_N + BP2_N + 255) / 256, 256, 0, stream>>>(W1l, W1r, W2l, W2r,
                                                                     bp1, bp2);

    // layer 1 aggregate + both dense matmuls via MFMA (h1 stays in LDS)
    gather1_kernel<<<(N + 3) / 4, 256, 0, stream>>>(xb, row_start, sorted_src, agg1b, N);
    gemm1_kernel<<<(N + T1_M - 1) / T1_M, 256, 0, stream>>>(xb, agg1b, bp1, bp2,
                                                            b1, ub, vv, N);
    // layer 2 aggregate (64 dims, bf16)
    gatheru_kernel<<<(N + 3) / 4, 256, 0, stream>>>(ub, row_start, sorted_src, aggu, N);

    // h2 = aggu + v + b2, fused with segment-max
    finalize_kernel<<<(N + SEG_NODES - 1) / SEG_NODES, 256, 0, stream>>>(
        aggu, vv, b2, batch, out, N);
}

// Round 14
// 132.795 us; speedup vs baseline: 2.4085x; 1.1144x over previous
//
#include <hip/hip_runtime.h>
#include <hip/hip_bf16.h>

#define IN_F 108   // concat(x[107], votes[1])
#define XD   107
#define HID  128
#define OUTD 64
#define SEG_NODES 64
#define BSH 6              // bucket = dst >> 6 (64 nodes per bucket)
#define BNODES 64
#define MAXBK 1024         // supports N <= 65536
#define EPB 4096           // edges per bscatter block
#define SRCMASK 0x03FFFFFF
#define BP1_N (8 * 7 * 64 * 8)   // [ct][ks][lane][j] fragment-packed W1 (K=224 pad)
#define BP2_N (8 * 4 * 64 * 8)   // fragment-packed [W2l|W2r] (K=128)

typedef unsigned short ushort_t;
typedef unsigned int uint_t;
typedef __attribute__((ext_vector_type(8))) short bf16x8;
typedef __attribute__((ext_vector_type(4))) float f32x4;

__device__ inline void atomicMaxF(float* addr, float val) {
    if (val >= 0.f) atomicMax((int*)addr, __float_as_int(val));
    else            atomicMin((unsigned int*)addr, __float_as_uint(val));
}

__device__ inline ushort_t f2bf(float f) {
    uint_t b = __float_as_uint(f);
    return (ushort_t)((b + 0x7fffu + ((b >> 16) & 1u)) >> 16);   // RNE
}

// ---- init: zero bcnt + out=-inf -----------------------------------------
__global__ void init0_kernel(int* bcnt, int nbk, float* out, int n) {
    int i = blockIdx.x * 256 + threadIdx.x;
    if (i < nbk) bcnt[i] = 0;
    if (i < n) out[i] = -__builtin_inff();
}

// ---- bucket sort stage A1: bucket histogram -----------------------------
__global__ __launch_bounds__(256) void bhist_kernel(const int* __restrict__ dst,
                                                    int* __restrict__ bcnt, int E, int nbk) {
    __shared__ int lh[MAXBK];
    for (int i = threadIdx.x; i < nbk; i += 256) lh[i] = 0;
    __syncthreads();
    int base = blockIdx.x * EPB;
    int end = min(base + EPB, E);
    for (int k = base + threadIdx.x; k < end; k += 256)
        atomicAdd(&lh[dst[k] >> BSH], 1);
    __syncthreads();
    for (int i = threadIdx.x; i < nbk; i += 256)
        if (lh[i] > 0) atomicAdd(&bcnt[i], lh[i]);
}

// ---- A2: exclusive scan of bucket counts (one wave) ---------------------
__global__ __launch_bounds__(64) void bscan_kernel(const int* __restrict__ bcnt,
                                                   int* __restrict__ bbase,
                                                   int* __restrict__ brsv,
                                                   int* __restrict__ row_start,
                                                   int nbk, int N, int E) {
    int lane = threadIdx.x;
    int carry = 0;
    for (int b = 0; b < nbk; b += 64) {
        int i = b + lane;
        int orig = (i < nbk) ? bcnt[i] : 0;
        int v = orig;
#pragma unroll
        for (int d = 1; d < 64; d <<= 1) {
            int t = __shfl_up(v, d);
            if (lane >= d) v += t;
        }
        if (i < nbk) {
            int ex = carry + v - orig;
            bbase[i] = ex;
            brsv[i] = ex;
        }
        carry += __shfl(v, 63);
    }
    if (lane == 0) {
        bbase[nbk] = E;
        row_start[N] = E;
    }
}

// ---- A3: scatter edges into bucket-grouped ebuf (packed uint) -----------
__global__ __launch_bounds__(256) void bscatter_kernel(const int* __restrict__ src,
                                                       const int* __restrict__ dst,
                                                       int* __restrict__ brsv,
                                                       uint_t* __restrict__ ebuf,
                                                       int E, int nbk) {
    __shared__ int lh[MAXBK];
    __shared__ int lofs[MAXBK];
    for (int i = threadIdx.x; i < nbk; i += 256) lh[i] = 0;
    __syncthreads();
    int base = blockIdx.x * EPB;
    int end = min(base + EPB, E);
    for (int k = base + threadIdx.x; k < end; k += 256)
        atomicAdd(&lh[dst[k] >> BSH], 1);
    __syncthreads();
    for (int i = threadIdx.x; i < nbk; i += 256)
        if (lh[i] > 0) lofs[i] = atomicAdd(&brsv[i], lh[i]);
    __syncthreads();
    for (int k = base + threadIdx.x; k < end; k += 256) {
        int d = dst[k];
        int pos = atomicAdd(&lofs[d >> BSH], 1);
        ebuf[pos] = (uint_t)src[k] | ((uint_t)(d & (BNODES - 1)) << 26);
    }
}

// ---- B: per-bucket CSR build (row_start + sorted_src) -------------------
__global__ __launch_bounds__(256) void bbuild_kernel(const uint_t* __restrict__ ebuf,
                                                     const int* __restrict__ bbase,
                                                     int* __restrict__ row_start,
                                                     int* __restrict__ sorted_src,
                                                     int N) {
    __shared__ int nh[BNODES];
    __shared__ int cur[BNODES];
    int b = blockIdx.x;
    int e0 = bbase[b], e1 = bbase[b + 1];
    int nlo = b << BSH;
    int nloc = min(BNODES, N - nlo);
    if (threadIdx.x < BNODES) nh[threadIdx.x] = 0;
    __syncthreads();
    for (int k = e0 + threadIdx.x; k < e1; k += 256)
        atomicAdd(&nh[ebuf[k] >> 26], 1);
    __syncthreads();
    if (threadIdx.x < 64) {
        int lane = threadIdx.x;
        int orig = nh[lane];
        int v = orig;
#pragma unroll
        for (int d = 1; d < 64; d <<= 1) {
            int t = __shfl_up(v, d);
            if (lane >= d) v += t;
        }
        int ex = e0 + v - orig;
        cur[lane] = ex;
        if (lane < nloc) row_start[nlo + lane] = ex;
    }
    __syncthreads();
    for (int k = e0 + threadIdx.x; k < e1; k += 256) {
        uint_t e = ebuf[k];
        int pos = atomicAdd(&cur[e >> 26], 1);
        sorted_src[pos] = (int)(e & SRCMASK);
    }
}

// ---- prep: xb (bf16 h0) + fragment-packed weights -----------------------
__global__ void prep_kernel(const float* __restrict__ x, const float* __restrict__ votes,
                            const float* __restrict__ W1l, const float* __restrict__ W1r,
                            const float* __restrict__ W2l, const float* __restrict__ W2r,
                            ushort_t* __restrict__ xb, ushort_t* __restrict__ bp1,
                            ushort_t* __restrict__ bp2, int N) {
    int idx = blockIdx.x * 256 + threadIdx.x;
    if (idx < N * IN_F) {
        int n = idx / IN_F, f = idx - n * IN_F;
        float v = (f < XD) ? x[n * XD + f] : votes[n];
        xb[idx] = f2bf(v);
    }
    if (idx < BP1_N) {
        int j = idx & 7;
        int lane = (idx >> 3) & 63;
        int rest = idx >> 9;
        int ks = rest % 7;
        int ct = rest / 7;
        int k = ks * 32 + (lane >> 4) * 8 + j;
        int col = ct * 16 + (lane & 15);
        float v = 0.f;
        if (k < IN_F) v = W1l[k * HID + col];
        else if (k < 2 * IN_F) v = W1r[(k - IN_F) * HID + col];
        bp1[idx] = f2bf(v);
    }
    int i2 = idx - BP1_N;
    if (i2 >= 0 && i2 < BP2_N) {
        int j = i2 & 7;
        int lane = (i2 >> 3) & 63;
        int ks = (i2 >> 9) & 3;
        int ct = i2 >> 11;
        int k = ks * 32 + (lane >> 4) * 8 + j;
        int col = ct * 16 + (lane & 15);
        float v = (col < OUTD) ? W2l[k * OUTD + col] : W2r[k * OUTD + (col - OUTD)];
        bp2[i2] = f2bf(v);
    }
}

// ---- fused: gather-mean (into LDS) + MFMA dense x2 ----------------------
// h1 = relu([agg|h0] @ [W1l;W1r] + b1);  [u|v] = h1 @ [W2l|W2r]
// Block 256 thr / 4 waves / 32 nodes. Wave w gathers nodes w*8..w*8+7.
#define T1_M 32
#define A_STRIDE_US 232
#define A_STRIDE_U  116
#define H1_STRIDE_US 136
__global__ __launch_bounds__(256) void fused1_kernel(
        const ushort_t* __restrict__ xb,
        const int* __restrict__ row_start, const int* __restrict__ sorted_src,
        const ushort_t* __restrict__ bp1, const ushort_t* __restrict__ bp2,
        const float* __restrict__ b1,
        ushort_t* __restrict__ ub, float* __restrict__ vv, int N) {
    __shared__ uint_t smem[T1_M * A_STRIDE_U];      // 14848 B
    int n0 = blockIdx.x * T1_M;
    const uint_t* xbu = (const uint_t*)xb;

    // phase A: stage h0 rows (uints 54..107) + zero pad (108..111)
    for (int i = threadIdx.x; i < T1_M * 54; i += 256) {
        int m = i / 54, c = i - m * 54;
        int n = n0 + m;
        smem[m * A_STRIDE_U + 54 + c] = (n < N) ? xbu[n * 54 + c] : 0u;
    }
    for (int i = threadIdx.x; i < T1_M * 4; i += 256) {
        int m = i >> 2, c = i & 3;
        smem[m * A_STRIDE_U + 108 + c] = 0u;
    }

    int lane = threadIdx.x & 63;
    int wid  = threadIdx.x >> 6;
    int h  = lane >> 5;
    int l2 = lane & 31;

    // phase B: gather-mean for this wave's 8 nodes -> LDS agg region (uints 0..53)
    for (int it = 0; it < 8; ++it) {
        int m = wid * 8 + it;
        int node = n0 + m;
        float a0 = 0.f, a1 = 0.f, a2 = 0.f, a3 = 0.f;
        int deg = 0;
        if (node < N) {
            int rs = row_start[node], re = row_start[node + 1];
            deg = re - rs;
            for (int k0 = rs; k0 < re; k0 += 64) {
                int cnt = min(64, re - k0);
                int sl = sorted_src[k0 + min(lane, cnt - 1)];
                int t = 0;
                for (; t + 8 <= cnt; t += 8) {
                    int s0 = __shfl(sl, t + h);
                    int s1 = __shfl(sl, t + 2 + h);
                    int s2 = __shfl(sl, t + 4 + h);
                    int s3 = __shfl(sl, t + 6 + h);
                    if (l2 < 27) {
                        uint2 w0 = *(const uint2*)(xb + s0 * IN_F + 4 * l2);
                        uint2 w1 = *(const uint2*)(xb + s1 * IN_F + 4 * l2);
                        uint2 w2 = *(const uint2*)(xb + s2 * IN_F + 4 * l2);
                        uint2 w3 = *(const uint2*)(xb + s3 * IN_F + 4 * l2);
                        a0 += __uint_as_float(w0.x << 16) + __uint_as_float(w1.x << 16)
                            + __uint_as_float(w2.x << 16) + __uint_as_float(w3.x << 16);
                        a1 += __uint_as_float(w0.x & 0xffff0000u) + __uint_as_float(w1.x & 0xffff0000u)
                            + __uint_as_float(w2.x & 0xffff0000u) + __uint_as_float(w3.x & 0xffff0000u);
                        a2 += __uint_as_float(w0.y << 16) + __uint_as_float(w1.y << 16)
                            + __uint_as_float(w2.y << 16) + __uint_as_float(w3.y << 16);
                        a3 += __uint_as_float(w0.y & 0xffff0000u) + __uint_as_float(w1.y & 0xffff0000u)
                            + __uint_as_float(w2.y & 0xffff0000u) + __uint_as_float(w3.y & 0xffff0000u);
                    }
                }
                for (; t < cnt; t += 2) {
                    int tt = min(t + h, cnt - 1);
                    int s = __shfl(sl, tt);
                    if (t + h < cnt && l2 < 27) {
                        uint2 w = *(const uint2*)(xb + s * IN_F + 4 * l2);
                        a0 += __uint_as_float(w.x << 16);
                        a1 += __uint_as_float(w.x & 0xffff0000u);
                        a2 += __uint_as_float(w.y << 16);
                        a3 += __uint_as_float(w.y & 0xffff0000u);
                    }
                }
            }
        }
        a0 += __shfl_xor(a0, 32);
        a1 += __shfl_xor(a1, 32);
        a2 += __shfl_xor(a2, 32);
        a3 += __shfl_xor(a3, 32);
        if (node < N && l2 < 27) {
            float inv = 1.f / fmaxf((float)deg, 1.f);
            ushort4 p;
            p.x = f2bf(a0 * inv);
            p.y = f2bf(a1 * inv);
            p.z = f2bf(a2 * inv);
            p.w = f2bf(a3 * inv);
            *(ushort4*)((ushort_t*)smem + m * A_STRIDE_US + 4 * l2) = p;
        }
    }
    __syncthreads();

    // phase C: MFMA layer 1
    int wrow = (wid & 1) << 4;
    int wcol = (wid >> 1) << 6;
    int arow = wrow + (lane & 15);
    int akoff = (lane >> 4) * 8;
    const ushort_t* sA = (const ushort_t*)smem;
    const bf16x8* bp1v = (const bf16x8*)bp1;

    f32x4 acc0 = {}, acc1 = {}, acc2_ = {}, acc3 = {};
    int ct0 = wcol >> 4;
#pragma unroll
    for (int ks = 0; ks < 7; ++ks) {
        bf16x8 af = *(const bf16x8*)(sA + arow * A_STRIDE_US + ks * 32 + akoff);
        bf16x8 bf0 = bp1v[((ct0 + 0) * 7 + ks) * 64 + lane];
        bf16x8 bf1 = bp1v[((ct0 + 1) * 7 + ks) * 64 + lane];
        bf16x8 bf2 = bp1v[((ct0 + 2) * 7 + ks) * 64 + lane];
        bf16x8 bf3 = bp1v[((ct0 + 3) * 7 + ks) * 64 + lane];
        acc0 = __builtin_amdgcn_mfma_f32_16x16x32_bf16(af, bf0, acc0, 0, 0, 0);
        acc1 = __builtin_amdgcn_mfma_f32_16x16x32_bf16(af, bf1, acc1, 0, 0, 0);
        acc2_ = __builtin_amdgcn_mfma_f32_16x16x32_bf16(af, bf2, acc2_, 0, 0, 0);
        acc3 = __builtin_amdgcn_mfma_f32_16x16x32_bf16(af, bf3, acc3, 0, 0, 0);
    }

    __syncthreads();
    ushort_t* sh1 = (ushort_t*)smem;
    {
        int colb = wcol + (lane & 15);
        int rowb = wrow + ((lane >> 4) << 2);
#pragma unroll
        for (int t = 0; t < 4; ++t) {
            f32x4 a = (t == 0) ? acc0 : (t == 1) ? acc1 : (t == 2) ? acc2_ : acc3;
            int col = colb + t * 16;
            float bj = b1[col];
#pragma unroll
            for (int r = 0; r < 4; ++r)
                sh1[(rowb + r) * H1_STRIDE_US + col] = f2bf(fmaxf(a[r] + bj, 0.f));
        }
    }
    __syncthreads();

    // phase D: MFMA layer 2 ([u|v])
    const bf16x8* bp2v = (const bf16x8*)bp2;
    f32x4 dcc0 = {}, dcc1 = {}, dcc2 = {}, dcc3 = {};
#pragma unroll
    for (int ks = 0; ks < 4; ++ks) {
        bf16x8 af = *(const bf16x8*)(sh1 + arow * H1_STRIDE_US + ks * 32 + akoff);
        bf16x8 bf0 = bp2v[((ct0 + 0) * 4 + ks) * 64 + lane];
        bf16x8 bf1 = bp2v[((ct0 + 1) * 4 + ks) * 64 + lane];
        bf16x8 bf2 = bp2v[((ct0 + 2) * 4 + ks) * 64 + lane];
        bf16x8 bf3 = bp2v[((ct0 + 3) * 4 + ks) * 64 + lane];
        dcc0 = __builtin_amdgcn_mfma_f32_16x16x32_bf16(af, bf0, dcc0, 0, 0, 0);
        dcc1 = __builtin_amdgcn_mfma_f32_16x16x32_bf16(af, bf1, dcc1, 0, 0, 0);
        dcc2 = __builtin_amdgcn_mfma_f32_16x16x32_bf16(af, bf2, dcc2, 0, 0, 0);
        dcc3 = __builtin_amdgcn_mfma_f32_16x16x32_bf16(af, bf3, dcc3, 0, 0, 0);
    }

    {
        int colb = wcol + (lane & 15);
        int rowb = wrow + ((lane >> 4) << 2);
#pragma unroll
        for (int t = 0; t < 4; ++t) {
            f32x4 a = (t == 0) ? dcc0 : (t == 1) ? dcc1 : (t == 2) ? dcc2 : dcc3;
            int col = colb + t * 16;
#pragma unroll
            for (int r = 0; r < 4; ++r) {
                int n = n0 + rowb + r;
                if (n < N) {
                    if (col < OUTD) ub[(n << 6) + col] = f2bf(a[r]);
                    else            vv[(n << 6) + (col - OUTD)] = a[r];
                }
            }
        }
    }
}

// ---- gather-mean of u (bf16, 64 dims; 8 neighbors/iter) -----------------
__global__ __launch_bounds__(256) void gatheru_kernel(
        const ushort_t* __restrict__ ub,
        const int* __restrict__ row_start, const int* __restrict__ sorted_src,
        float* __restrict__ aggu, int N) {
    int node = (blockIdx.x * 256 + threadIdx.x) >> 6;
    int lane = threadIdx.x & 63;
    if (node >= N) return;
    int rs = row_start[node], re = row_start[node + 1];
    int g  = lane >> 4;
    int l4 = lane & 15;
    float a0 = 0.f, a1 = 0.f, a2 = 0.f, a3 = 0.f;
    for (int k0 = rs; k0 < re; k0 += 64) {
        int cnt = min(64, re - k0);
        int sl = sorted_src[k0 + min(lane, cnt - 1)];
        int t = 0;
        for (; t + 8 <= cnt; t += 8) {
            int s0 = __shfl(sl, t + g);
            int s1 = __shfl(sl, t + 4 + g);
            uint2 w0 = *(const uint2*)(ub + (s0 << 6) + 4 * l4);
            uint2 w1 = *(const uint2*)(ub + (s1 << 6) + 4 * l4);
            a0 += __uint_as_float(w0.x << 16) + __uint_as_float(w1.x << 16);
            a1 += __uint_as_float(w0.x & 0xffff0000u) + __uint_as_float(w1.x & 0xffff0000u);
            a2 += __uint_as_float(w0.y << 16) + __uint_as_float(w1.y << 16);
            a3 += __uint_as_float(w0.y & 0xffff0000u) + __uint_as_float(w1.y & 0xffff0000u);
        }
        for (; t < cnt; t += 4) {
            int tt = min(t + g, cnt - 1);
            int s = __shfl(sl, tt);
            if (t + g < cnt) {
                uint2 w = *(const uint2*)(ub + (s << 6) + 4 * l4);
                a0 += __uint_as_float(w.x << 16);
                a1 += __uint_as_float(w.x & 0xffff0000u);
                a2 += __uint_as_float(w.y << 16);
                a3 += __uint_as_float(w.y & 0xffff0000u);
            }
        }
    }
    a0 += __shfl_xor(a0, 16); a0 += __shfl_xor(a0, 32);
    a1 += __shfl_xor(a1, 16); a1 += __shfl_xor(a1, 32);
    a2 += __shfl_xor(a2, 16); a2 += __shfl_xor(a2, 32);
    a3 += __shfl_xor(a3, 16); a3 += __shfl_xor(a3, 32);
    float inv = 1.f / fmaxf((float)(re - rs), 1.f);
    if (lane < 16) {
        *(float4*)(aggu + (node << 6) + 4 * lane) =
            make_float4(a0 * inv, a1 * inv, a2 * inv, a3 * inv);
    }
}

// ---- finalize: h2 = aggu + v + b2, then run-length segment-max ----------
__global__ __launch_bounds__(256) void finalize_kernel(
        const float* __restrict__ aggu, const float* __restrict__ vv,
        const float* __restrict__ b2, const int* __restrict__ batch,
        float* __restrict__ out, int N) {
    int j  = threadIdx.x & 63;
    int nq = threadIdx.x >> 6;
    int n0 = blockIdx.x * SEG_NODES;
    float bj = b2[j];
    int curg = -1;
    float curm = -__builtin_inff();
    for (int m = nq; m < SEG_NODES; m += 4) {
        int n = n0 + m;
        if (n >= N) break;
        int g = batch[n];
        float v = aggu[(n << 6) + j] + vv[(n << 6) + j] + bj;
        if (g != curg) {
            if (curg >= 0) atomicMaxF(&out[(curg << 6) + j], curm);
            curg = g;
            curm = v;
        } else {
            curm = fmaxf(curm, v);
        }
    }
    if (curg >= 0) atomicMaxF(&out[(curg << 6) + j], curm);
}

static inline size_t align256(size_t v) { return (v + 255) & ~(size_t)255; }

extern "C" void kernel_launch(void* const* d_in, const int* in_sizes, int n_in,
                              void* d_out, int out_size, void* d_ws, size_t ws_size,
                              hipStream_t stream) {
    const float* x     = (const float*)d_in[0];
    const float* votes = (const float*)d_in[1];
    const int*   eidx  = (const int*)d_in[2];
    const int*   batch = (const int*)d_in[3];
    const float* W1l   = (const float*)d_in[4];
    const float* b1    = (const float*)d_in[5];
    const float* W1r   = (const float*)d_in[6];
    const float* W2l   = (const float*)d_in[7];
    const float* b2    = (const float*)d_in[8];
    const float* W2r   = (const float*)d_in[9];
    float* out = (float*)d_out;

    const int N = in_sizes[1];
    const int E = in_sizes[2] / 2;
    const int* src = eidx;
    const int* dst = eidx + E;
    const int nbk = (N + BNODES - 1) >> BSH;   // 782 for N=50000

    char* ws = (char*)d_ws;
    size_t off = 0;
    int* bcnt       = (int*)(ws + off); off = align256(off + (size_t)nbk * 4);
    int* bbase      = (int*)(ws + off); off = align256(off + (size_t)(nbk + 1) * 4);
    int* brsv       = (int*)(ws + off); off = align256(off + (size_t)nbk * 4);
    int* row_start  = (int*)(ws + off); off = align256(off + (size_t)(N + 1) * 4);
    uint_t* ebuf    = (uint_t*)(ws + off); off = align256(off + (size_t)E * 4);
    int* sorted_src = (int*)(ws + off); off = align256(off + (size_t)E * 4);
    ushort_t* xb    = (ushort_t*)(ws + off); off = align256(off + (size_t)N * IN_F * 2);
    ushort_t* ub    = (ushort_t*)(ws + off); off = align256(off + (size_t)N * OUTD * 2);
    float* vv       = (float*)(ws + off); off = align256(off + (size_t)N * OUTD * 4);
    float* aggu     = (float*)(ws + off); off = align256(off + (size_t)N * OUTD * 4);
    ushort_t* bp1   = (ushort_t*)(ws + off); off = align256(off + (size_t)BP1_N * 2);
    ushort_t* bp2   = (ushort_t*)(ws + off); off = align256(off + (size_t)BP2_N * 2);

    // init (bcnt zero + out=-inf)
    {
        int mx = max(nbk, out_size);
        init0_kernel<<<(mx + 255) / 256, 256, 0, stream>>>(bcnt, nbk, out, out_size);
    }

    // bucket counting sort -> CSR
    int nebl = (E + EPB - 1) / EPB;
    bhist_kernel<<<nebl, 256, 0, stream>>>(dst, bcnt, E, nbk);
    bscan_kernel<<<1, 64, 0, stream>>>(bcnt, bbase, brsv, row_start, nbk, N, E);
    bscatter_kernel<<<nebl, 256, 0, stream>>>(src, dst, brsv, ebuf, E, nbk);
    bbuild_kernel<<<nbk, 256, 0, stream>>>(ebuf, bbase, row_start, sorted_src, N);

    // conversions (xb + fragment-packed weights)
    prep_kernel<<<(N * IN_F + 255) / 256, 256, 0, stream>>>(x, votes, W1l, W1r, W2l, W2r,
                                                            xb, bp1, bp2, N);

    // fused gather + both dense matmuls via MFMA (agg + h1 stay in LDS)
    fused1_kernel<<<(N + T1_M - 1) / T1_M, 256, 0, stream>>>(xb, row_start, sorted_src,
                                                             bp1, bp2, b1, ub, vv, N);
    // layer 2 aggregate (64 dims, bf16)
    gatheru_kernel<<<(N + 3) / 4, 256, 0, stream>>>(ub, row_start, sorted_src, aggu, N);

    // h2 = aggu + v + b2, fused with segment-max
    finalize_kernel<<<(N + SEG_NODES - 1) / SEG_NODES, 256, 0, stream>>>(
        aggu, vv, b2, batch, out, N);
}